// Round 1
// baseline (9009.981 us; speedup 1.0000x reference)
//
#include <hip/hip_runtime.h>

// Problem constants (fixed by the reference)
#define D_MODEL   256
#define NQ        1600
#define BATCH     2
#define NHEAD     8
#define HDIM      32
#define S_TOTAL   5440
#define D_FFN     1024
#define NUM_LAYERS 6

#define M_Q   (BATCH * NQ)       // 3200
#define M_V   (BATCH * S_TOTAL)  // 10880
#define ROW_ELEMS ((size_t)M_Q * D_MODEL)   // 819200

// ---------------------------------------------------------------------------
// GEMM: C[M,N] = A[M,K] @ W[N,K]^T + bias[N]   (optional ReLU)
// Requires: M % 64 == 0, N % 64 == 0, K % 16 == 0 (true for all call sites)
// ---------------------------------------------------------------------------
template <int RELU>
__global__ __launch_bounds__(256) void gemm_bias(const float* __restrict__ A,
                                                 const float* __restrict__ W,
                                                 const float* __restrict__ bias,
                                                 float* __restrict__ C,
                                                 int M, int N, int K)
{
    __shared__ float As[64][17];
    __shared__ float Bs[64][17];
    const int tid = threadIdx.x;
    const int tx = tid & 15;          // 0..15 -> N dim
    const int ty = tid >> 4;          // 0..15 -> M dim
    const int bm = blockIdx.x * 64;
    const int bn = blockIdx.y * 64;

    const int lr = tid >> 2;          // 0..63 row to load
    const int lc = (tid & 3) * 4;     // 0,4,8,12 col within k-tile

    float acc[4][4] = {};

    for (int k0 = 0; k0 < K; k0 += 16) {
        float4 a4 = *(const float4*)(A + (size_t)(bm + lr) * K + k0 + lc);
        As[lr][lc + 0] = a4.x; As[lr][lc + 1] = a4.y;
        As[lr][lc + 2] = a4.z; As[lr][lc + 3] = a4.w;
        float4 w4 = *(const float4*)(W + (size_t)(bn + lr) * K + k0 + lc);
        Bs[lr][lc + 0] = w4.x; Bs[lr][lc + 1] = w4.y;
        Bs[lr][lc + 2] = w4.z; Bs[lr][lc + 3] = w4.w;
        __syncthreads();
#pragma unroll
        for (int kk = 0; kk < 16; ++kk) {
            float a[4], w[4];
#pragma unroll
            for (int i = 0; i < 4; ++i) a[i] = As[ty * 4 + i][kk];
#pragma unroll
            for (int j = 0; j < 4; ++j) w[j] = Bs[tx * 4 + j][kk];
#pragma unroll
            for (int i = 0; i < 4; ++i)
#pragma unroll
                for (int j = 0; j < 4; ++j)
                    acc[i][j] = fmaf(a[i], w[j], acc[i][j]);
        }
        __syncthreads();
    }

#pragma unroll
    for (int i = 0; i < 4; ++i) {
        const int m = bm + ty * 4 + i;
#pragma unroll
        for (int j = 0; j < 4; ++j) {
            const int n = bn + tx * 4 + j;
            float v = acc[i][j] + bias[n];
            if (RELU) v = fmaxf(v, 0.f);
            C[(size_t)m * N + n] = v;
        }
    }
}

// ---------------------------------------------------------------------------
// Elementwise add (float4): o = a + b
// ---------------------------------------------------------------------------
__global__ __launch_bounds__(256) void add_kernel(const float* __restrict__ a,
                                                  const float* __restrict__ b,
                                                  float* __restrict__ o, int n4)
{
    int i = blockIdx.x * 256 + threadIdx.x;
    if (i < n4) {
        float4 x = ((const float4*)a)[i];
        float4 y = ((const float4*)b)[i];
        float4 z; z.x = x.x + y.x; z.y = x.y + y.y; z.z = x.z + y.z; z.w = x.w + y.w;
        ((float4*)o)[i] = z;
    }
}

// ---------------------------------------------------------------------------
// Self-attention: one wave (64 lanes) per (b, h, q). Online softmax over 1600
// keys (25 per lane), LDS column-reduction at the end.
// Layout: qh/kh/vh are (B*NQ, 256) with head h at cols [h*32, h*32+32).
// ---------------------------------------------------------------------------
__global__ __launch_bounds__(64) void attn_kernel(const float* __restrict__ qh,
                                                  const float* __restrict__ kh,
                                                  const float* __restrict__ vh,
                                                  float* __restrict__ outp)
{
    const int blk = blockIdx.x;            // (b*NHEAD + h)*NQ + q
    const int q   = blk % NQ;
    const int bh  = blk / NQ;
    const int h   = bh & (NHEAD - 1);
    const int b   = bh >> 3;
    const int lane = threadIdx.x;

    const size_t base = (size_t)b * NQ * D_MODEL + (size_t)h * HDIM;
    const float* qrow = qh + base + (size_t)q * D_MODEL;

    float4 qv[8];
#pragma unroll
    for (int i = 0; i < 8; ++i) qv[i] = ((const float4*)qrow)[i];

    float m = -1e30f, l = 0.f;
    float acc[32] = {};

    for (int k = lane; k < NQ; k += 64) {
        const float* krow = kh + base + (size_t)k * D_MODEL;
        float dot = 0.f;
#pragma unroll
        for (int i = 0; i < 8; ++i) {
            float4 kv = ((const float4*)krow)[i];
            dot = fmaf(qv[i].x, kv.x, dot);
            dot = fmaf(qv[i].y, kv.y, dot);
            dot = fmaf(qv[i].z, kv.z, dot);
            dot = fmaf(qv[i].w, kv.w, dot);
        }
        dot *= 0.1767766952966369f;  // 1/sqrt(32)
        float mnew = fmaxf(m, dot);
        float corr = __expf(m - mnew);
        float p    = __expf(dot - mnew);
        m = mnew;
        l = l * corr + p;
        const float* vrow = vh + base + (size_t)k * D_MODEL;
#pragma unroll
        for (int i = 0; i < 8; ++i) {
            float4 vv = ((const float4*)vrow)[i];
            acc[i*4+0] = fmaf(acc[i*4+0], corr, p * vv.x);
            acc[i*4+1] = fmaf(acc[i*4+1], corr, p * vv.y);
            acc[i*4+2] = fmaf(acc[i*4+2], corr, p * vv.z);
            acc[i*4+3] = fmaf(acc[i*4+3], corr, p * vv.w);
        }
    }

    // global max across lanes
    float mg = m;
#pragma unroll
    for (int off = 32; off; off >>= 1) mg = fmaxf(mg, __shfl_xor(mg, off));
    const float f = __expf(m - mg);

    __shared__ float red[64][33];
    __shared__ float redl[64];
    redl[lane] = l * f;
#pragma unroll
    for (int c = 0; c < 32; ++c) red[lane][c] = acc[c] * f;
    __syncthreads();

    if (lane < 32) {
        float s = 0.f, lt = 0.f;
        for (int i = 0; i < 64; ++i) { s += red[i][lane]; lt += redl[i]; }
        outp[base + (size_t)q * D_MODEL + lane] = s / lt;
    }
}

// ---------------------------------------------------------------------------
// Fused residual + LayerNorm: out_row = LN(x_row + t2_row) * g + b
// One block (256 threads) per row of 256. In-place safe (x == outp).
// ---------------------------------------------------------------------------
__global__ __launch_bounds__(256) void residual_ln_kernel(const float* __restrict__ x,
                                                          const float* __restrict__ t2,
                                                          const float* __restrict__ g,
                                                          const float* __restrict__ bt,
                                                          float* __restrict__ outp)
{
    const int row = blockIdx.x;
    const int c = threadIdx.x;
    const size_t idx = (size_t)row * D_MODEL + c;
    float v = x[idx] + t2[idx];

    float s = v, s2 = v * v;
#pragma unroll
    for (int off = 32; off; off >>= 1) {
        s  += __shfl_xor(s,  off);
        s2 += __shfl_xor(s2, off);
    }
    __shared__ float ws[4], ws2[4];
    const int wid = c >> 6;
    if ((c & 63) == 0) { ws[wid] = s; ws2[wid] = s2; }
    __syncthreads();
    const float tot  = ws[0] + ws[1] + ws[2] + ws[3];
    const float tot2 = ws2[0] + ws2[1] + ws2[2] + ws2[3];
    const float mu  = tot * (1.f / 256.f);
    const float var = tot2 * (1.f / 256.f) - mu * mu;
    outp[idx] = (v - mu) * rsqrtf(var + 1e-5f) * g[c] + bt[c];
}

// ---------------------------------------------------------------------------
// Softmax over 16 elements per row (attention weights). One thread per row.
// ---------------------------------------------------------------------------
__global__ __launch_bounds__(256) void softmax16_kernel(float* __restrict__ aw, int rows)
{
    int r = blockIdx.x * 256 + threadIdx.x;
    if (r >= rows) return;
    float* p = aw + (size_t)r * 16;
    float v[16];
    float mx = -1e30f;
#pragma unroll
    for (int i = 0; i < 16; ++i) { v[i] = p[i]; mx = fmaxf(mx, v[i]); }
    float sum = 0.f;
#pragma unroll
    for (int i = 0; i < 16; ++i) { v[i] = __expf(v[i] - mx); sum += v[i]; }
    const float inv = 1.f / sum;
#pragma unroll
    for (int i = 0; i < 16; ++i) p[i] = v[i] * inv;
}

// ---------------------------------------------------------------------------
// Deformable sampling. Block per (b,q); thread = (head h = tid>>5, chan c = tid&31).
// value: (B, S_TOTAL, NHEAD, HDIM); off: (B*NQ, 256) as (h,l,p,2);
// aw (post-softmax): (B*NQ, 128) as (h,l,p); ref: (B, NQ, 4, 2).
// ---------------------------------------------------------------------------
__global__ __launch_bounds__(256) void sample_kernel(const float* __restrict__ value,
                                                     const float* __restrict__ off,
                                                     const float* __restrict__ aw,
                                                     const float* __restrict__ ref,
                                                     float* __restrict__ outp)
{
    const int bq = blockIdx.x;              // b*NQ + q
    const int b  = bq / NQ;
    const int h  = threadIdx.x >> 5;
    const int c  = threadIdx.x & 31;

    const float* offrow = off + (size_t)bq * 256 + h * 32;   // (l,p,2): l*8+p*2
    const float* awrow  = aw  + (size_t)bq * 128 + h * 16;   // (l,p):   l*4+p
    const float* refrow = ref + (size_t)bq * 8;              // (l,2)

    const int   HL[4] = {64, 32, 16, 8};
    const int   WLv[4] = {64, 32, 16, 8};
    const int   S0[4] = {0, 4096, 5120, 5376};

    float acc = 0.f;
#pragma unroll
    for (int l = 0; l < 4; ++l) {
        const int Hl = HL[l], Wl = WLv[l];
        const float rx = refrow[l * 2 + 0];
        const float ry = refrow[l * 2 + 1];
        const size_t lvl_base = ((size_t)b * S_TOTAL + S0[l]);
#pragma unroll
        for (int p = 0; p < 4; ++p) {
            const float ox = offrow[l * 8 + p * 2 + 0];
            const float oy = offrow[l * 8 + p * 2 + 1];
            const float w  = awrow[l * 4 + p];
            // loc = ref + off/[W,H];  x = loc_x*W - 0.5, y = loc_y*H - 0.5
            const float locx = rx + ox / (float)Wl;
            const float locy = ry + oy / (float)Hl;
            const float x = locx * (float)Wl - 0.5f;
            const float y = locy * (float)Hl - 0.5f;
            const float x0f = floorf(x), y0f = floorf(y);
            const float wx1 = x - x0f, wy1 = y - y0f;
            const int x0 = (int)x0f, y0 = (int)y0f;
#pragma unroll
            for (int dy = 0; dy < 2; ++dy) {
                const int yi = y0 + dy;
                const float wy = dy ? wy1 : (1.f - wy1);
                const bool vy = (yi >= 0) && (yi <= Hl - 1);
                const int yc = min(max(yi, 0), Hl - 1);
#pragma unroll
                for (int dx = 0; dx < 2; ++dx) {
                    const int xi = x0 + dx;
                    const float wx = dx ? wx1 : (1.f - wx1);
                    const bool vx = (xi >= 0) && (xi <= Wl - 1);
                    const int xc = min(max(xi, 0), Wl - 1);
                    const float g = value[((lvl_base + (size_t)yc * Wl + xc) * NHEAD + h) * HDIM + c];
                    acc += (vx && vy) ? g * (wx * wy * w) : 0.f;
                }
            }
        }
    }
    outp[(size_t)bq * D_MODEL + h * 32 + c] = acc;
}

// ---------------------------------------------------------------------------
// Host-side orchestration
// ---------------------------------------------------------------------------
extern "C" void kernel_launch(void* const* d_in, const int* in_sizes, int n_in,
                              void* d_out, int out_size, void* d_ws, size_t ws_size,
                              hipStream_t stream)
{
    const float* tgt  = (const float*)d_in[0];
    const float* qpos = (const float*)d_in[1];
    const float* refp = (const float*)d_in[2];
    const float* src  = (const float*)d_in[3];

    // Workspace carve-up (floats)
    float* bufA  = (float*)d_ws;               // 819200
    float* bufB1 = bufA  + ROW_ELEMS;          // 819200
    float* bufB2 = bufB1 + ROW_ELEMS;          // 819200
    float* bufB3 = bufB2 + ROW_ELEMS;          // 819200
    float* bufV  = bufB3 + ROW_ELEMS;          // 2785280 (value proj)
    float* bufF  = bufV  + (size_t)M_V * D_MODEL;  // 3276800 (ffn hidden)

    float* out = (float*)d_out;

    // out = tgt
    hipMemcpyAsync(out, tgt, sizeof(float) * ROW_ELEMS, hipMemcpyDeviceToDevice, stream);

    const dim3 gQ(M_Q / 64, D_MODEL / 64);     // (50, 4)
    const dim3 gV(M_V / 64, D_MODEL / 64);     // (170, 4)
    const dim3 gAw(M_Q / 64, 128 / 64);        // (50, 2)
    const dim3 gF1(M_Q / 64, D_FFN / 64);      // (50, 16)

    for (int l = 0; l < NUM_LAYERS; ++l) {
        const float* sa_w_q  = (const float*)d_in[4]  + (size_t)l * 65536;
        const float* sa_b_q  = (const float*)d_in[5]  + (size_t)l * 256;
        const float* sa_w_k  = (const float*)d_in[6]  + (size_t)l * 65536;
        const float* sa_b_k  = (const float*)d_in[7]  + (size_t)l * 256;
        const float* sa_w_v  = (const float*)d_in[8]  + (size_t)l * 65536;
        const float* sa_b_v  = (const float*)d_in[9]  + (size_t)l * 256;
        const float* sa_w_o  = (const float*)d_in[10] + (size_t)l * 65536;
        const float* sa_b_o  = (const float*)d_in[11] + (size_t)l * 256;
        const float* ln2_g   = (const float*)d_in[12] + (size_t)l * 256;
        const float* ln2_b   = (const float*)d_in[13] + (size_t)l * 256;
        const float* ca_w_off  = (const float*)d_in[14] + (size_t)l * 65536;
        const float* ca_b_off  = (const float*)d_in[15] + (size_t)l * 256;
        const float* ca_w_attn = (const float*)d_in[16] + (size_t)l * 32768;
        const float* ca_b_attn = (const float*)d_in[17] + (size_t)l * 128;
        const float* ca_w_val  = (const float*)d_in[18] + (size_t)l * 65536;
        const float* ca_b_val  = (const float*)d_in[19] + (size_t)l * 256;
        const float* ca_w_out  = (const float*)d_in[20] + (size_t)l * 65536;
        const float* ca_b_out  = (const float*)d_in[21] + (size_t)l * 256;
        const float* ln1_g   = (const float*)d_in[22] + (size_t)l * 256;
        const float* ln1_b   = (const float*)d_in[23] + (size_t)l * 256;
        const float* ffn_w1  = (const float*)d_in[24] + (size_t)l * 262144;
        const float* ffn_b1  = (const float*)d_in[25] + (size_t)l * 1024;
        const float* ffn_w2  = (const float*)d_in[26] + (size_t)l * 262144;
        const float* ffn_b2  = (const float*)d_in[27] + (size_t)l * 256;
        const float* ln3_g   = (const float*)d_in[28] + (size_t)l * 256;
        const float* ln3_b   = (const float*)d_in[29] + (size_t)l * 256;

        // ---- Self-attention ----
        add_kernel<<<800, 256, 0, stream>>>(out, qpos, bufA, (int)(ROW_ELEMS / 4));
        gemm_bias<0><<<gQ, 256, 0, stream>>>(bufA, sa_w_q, sa_b_q, bufB1, M_Q, 256, 256);
        gemm_bias<0><<<gQ, 256, 0, stream>>>(bufA, sa_w_k, sa_b_k, bufB2, M_Q, 256, 256);
        gemm_bias<0><<<gQ, 256, 0, stream>>>(out,  sa_w_v, sa_b_v, bufB3, M_Q, 256, 256);
        attn_kernel<<<BATCH * NHEAD * NQ, 64, 0, stream>>>(bufB1, bufB2, bufB3, bufA);
        gemm_bias<0><<<gQ, 256, 0, stream>>>(bufA, sa_w_o, sa_b_o, bufB1, M_Q, 256, 256);
        residual_ln_kernel<<<M_Q, 256, 0, stream>>>(out, bufB1, ln2_g, ln2_b, out);

        // ---- Deformable cross-attention ----
        add_kernel<<<800, 256, 0, stream>>>(out, qpos, bufA, (int)(ROW_ELEMS / 4));
        gemm_bias<0><<<gV, 256, 0, stream>>>(src, ca_w_val, ca_b_val, bufV, M_V, 256, 256);
        gemm_bias<0><<<gQ, 256, 0, stream>>>(bufA, ca_w_off, ca_b_off, bufB1, M_Q, 256, 256);
        gemm_bias<0><<<gAw, 256, 0, stream>>>(bufA, ca_w_attn, ca_b_attn, bufB2, M_Q, 128, 256);
        softmax16_kernel<<<(M_Q * NHEAD + 255) / 256, 256, 0, stream>>>(bufB2, M_Q * NHEAD);
        sample_kernel<<<M_Q, 256, 0, stream>>>(bufV, bufB1, bufB2, refp, bufB3);
        gemm_bias<0><<<gQ, 256, 0, stream>>>(bufB3, ca_w_out, ca_b_out, bufA, M_Q, 256, 256);
        residual_ln_kernel<<<M_Q, 256, 0, stream>>>(out, bufA, ln1_g, ln1_b, out);

        // ---- FFN ----
        gemm_bias<1><<<gF1, 256, 0, stream>>>(out, ffn_w1, ffn_b1, bufF, M_Q, D_FFN, 256);
        gemm_bias<0><<<gQ, 256, 0, stream>>>(bufF, ffn_w2, ffn_b2, bufA, M_Q, 256, D_FFN);
        residual_ln_kernel<<<M_Q, 256, 0, stream>>>(out, bufA, ln3_g, ln3_b, out);
    }

    (void)in_sizes; (void)n_in; (void)out_size; (void)ws_size;
}

// Round 2
// 3216.951 us; speedup vs baseline: 2.8008x; 2.8008x over previous
//
#include <hip/hip_runtime.h>

// Problem constants (fixed by the reference)
#define D_MODEL   256
#define NQ        1600
#define BATCH     2
#define NHEAD     8
#define HDIM      32
#define S_TOTAL   5440
#define D_FFN     1024
#define NUM_LAYERS 6

#define M_Q   (BATCH * NQ)       // 3200
#define M_V   (BATCH * S_TOTAL)  // 10880
#define ROW_ELEMS ((size_t)M_Q * D_MODEL)   // 819200

// ---------------------------------------------------------------------------
// GEMM: C[M,N] = A[M,K] @ W[N,K]^T + bias[N]   (optional ReLU)
// Requires: M % 64 == 0, N % 64 == 0, K % 16 == 0 (true for all call sites)
// ---------------------------------------------------------------------------
template <int RELU>
__global__ __launch_bounds__(256) void gemm_bias(const float* __restrict__ A,
                                                 const float* __restrict__ W,
                                                 const float* __restrict__ bias,
                                                 float* __restrict__ C,
                                                 int M, int N, int K)
{
    __shared__ float As[64][17];
    __shared__ float Bs[64][17];
    const int tid = threadIdx.x;
    const int tx = tid & 15;          // 0..15 -> N dim
    const int ty = tid >> 4;          // 0..15 -> M dim
    const int bm = blockIdx.x * 64;
    const int bn = blockIdx.y * 64;

    const int lr = tid >> 2;          // 0..63 row to load
    const int lc = (tid & 3) * 4;     // 0,4,8,12 col within k-tile

    float acc[4][4] = {};

    for (int k0 = 0; k0 < K; k0 += 16) {
        float4 a4 = *(const float4*)(A + (size_t)(bm + lr) * K + k0 + lc);
        As[lr][lc + 0] = a4.x; As[lr][lc + 1] = a4.y;
        As[lr][lc + 2] = a4.z; As[lr][lc + 3] = a4.w;
        float4 w4 = *(const float4*)(W + (size_t)(bn + lr) * K + k0 + lc);
        Bs[lr][lc + 0] = w4.x; Bs[lr][lc + 1] = w4.y;
        Bs[lr][lc + 2] = w4.z; Bs[lr][lc + 3] = w4.w;
        __syncthreads();
#pragma unroll
        for (int kk = 0; kk < 16; ++kk) {
            float a[4], w[4];
#pragma unroll
            for (int i = 0; i < 4; ++i) a[i] = As[ty * 4 + i][kk];
#pragma unroll
            for (int j = 0; j < 4; ++j) w[j] = Bs[tx * 4 + j][kk];
#pragma unroll
            for (int i = 0; i < 4; ++i)
#pragma unroll
                for (int j = 0; j < 4; ++j)
                    acc[i][j] = fmaf(a[i], w[j], acc[i][j]);
        }
        __syncthreads();
    }

#pragma unroll
    for (int i = 0; i < 4; ++i) {
        const int m = bm + ty * 4 + i;
#pragma unroll
        for (int j = 0; j < 4; ++j) {
            const int n = bn + tx * 4 + j;
            float v = acc[i][j] + bias[n];
            if (RELU) v = fmaxf(v, 0.f);
            C[(size_t)m * N + n] = v;
        }
    }
}

// ---------------------------------------------------------------------------
// Elementwise add (float4): o = a + b
// ---------------------------------------------------------------------------
__global__ __launch_bounds__(256) void add_kernel(const float* __restrict__ a,
                                                  const float* __restrict__ b,
                                                  float* __restrict__ o, int n4)
{
    int i = blockIdx.x * 256 + threadIdx.x;
    if (i < n4) {
        float4 x = ((const float4*)a)[i];
        float4 y = ((const float4*)b)[i];
        float4 z; z.x = x.x + y.x; z.y = x.y + y.y; z.z = x.z + y.z; z.w = x.w + y.w;
        ((float4*)o)[i] = z;
    }
}

// ---------------------------------------------------------------------------
// Self-attention, block-tiled flash style.
// Grid: (B*NHEAD, NQ/32). Block: 256 threads.
// Thread t: query qi = t>>3 (32 per block), key-lane kl = t&7.
// K/V staged in LDS in 64-key tiles, pad to 36 floats (16B-aligned rows,
// 8 distinct rows per wave access -> conflict-free broadcast).
// Per-thread online softmax over its strided key subset (200 keys),
// 2-key batched updates; final merge across the 8 lanes sharing a query.
// ---------------------------------------------------------------------------
#define AQT 32
#define AKT 64

__global__ __launch_bounds__(256) void attn_kernel(const float* __restrict__ qh,
                                                   const float* __restrict__ kh,
                                                   const float* __restrict__ vh,
                                                   float* __restrict__ outp)
{
    const int bh = blockIdx.x;
    const int h  = bh & (NHEAD - 1);
    const int b  = bh >> 3;
    const int t  = threadIdx.x;
    const int qi = t >> 3;          // 0..31
    const int kl = t & 7;           // 0..7
    const int q  = blockIdx.y * AQT + qi;

    const size_t base = (size_t)b * NQ * D_MODEL + (size_t)h * HDIM;

    __shared__ float k_lds[AKT][36];
    __shared__ float v_lds[AKT][36];

    // Q row in registers
    float4 qv[8];
    {
        const float* qrow = qh + base + (size_t)q * D_MODEL;
#pragma unroll
        for (int i = 0; i < 8; ++i) qv[i] = ((const float4*)qrow)[i];
    }

    float m = -1e30f, l = 0.f;
    float acc[32] = {};

    const int r0 = t >> 3,         c0 = t & 7;          // idx t
    const int r1 = (t + 256) >> 3, c1 = t & 7;          // idx t+256

    for (int k0 = 0; k0 < NQ; k0 += AKT) {
        __syncthreads();
        {
            const float4 ka = ((const float4*)(kh + base + (size_t)(k0 + r0) * D_MODEL))[c0];
            const float4 kb = ((const float4*)(kh + base + (size_t)(k0 + r1) * D_MODEL))[c1];
            const float4 va = ((const float4*)(vh + base + (size_t)(k0 + r0) * D_MODEL))[c0];
            const float4 vb = ((const float4*)(vh + base + (size_t)(k0 + r1) * D_MODEL))[c1];
            *(float4*)&k_lds[r0][c0 * 4] = ka;
            *(float4*)&k_lds[r1][c1 * 4] = kb;
            *(float4*)&v_lds[r0][c0 * 4] = va;
            *(float4*)&v_lds[r1][c1 * 4] = vb;
        }
        __syncthreads();

#pragma unroll
        for (int kk = 0; kk < 4; ++kk) {
            const int ka_row = kk * 16 + kl;
            const int kb_row = kk * 16 + 8 + kl;
            float d0a = 0.f, d0b = 0.f, d1a = 0.f, d1b = 0.f;
#pragma unroll
            for (int c = 0; c < 8; c += 2) {
                float4 x0 = *(const float4*)&k_lds[ka_row][c * 4];
                float4 x1 = *(const float4*)&k_lds[ka_row][c * 4 + 4];
                float4 y0 = *(const float4*)&k_lds[kb_row][c * 4];
                float4 y1 = *(const float4*)&k_lds[kb_row][c * 4 + 4];
                d0a = fmaf(x0.x, qv[c].x, d0a);   d0a = fmaf(x0.y, qv[c].y, d0a);
                d0a = fmaf(x0.z, qv[c].z, d0a);   d0a = fmaf(x0.w, qv[c].w, d0a);
                d0b = fmaf(x1.x, qv[c+1].x, d0b); d0b = fmaf(x1.y, qv[c+1].y, d0b);
                d0b = fmaf(x1.z, qv[c+1].z, d0b); d0b = fmaf(x1.w, qv[c+1].w, d0b);
                d1a = fmaf(y0.x, qv[c].x, d1a);   d1a = fmaf(y0.y, qv[c].y, d1a);
                d1a = fmaf(y0.z, qv[c].z, d1a);   d1a = fmaf(y0.w, qv[c].w, d1a);
                d1b = fmaf(y1.x, qv[c+1].x, d1b); d1b = fmaf(y1.y, qv[c+1].y, d1b);
                d1b = fmaf(y1.z, qv[c+1].z, d1b); d1b = fmaf(y1.w, qv[c+1].w, d1b);
            }
            const float s0 = (d0a + d0b) * 0.1767766952966369f;
            const float s1 = (d1a + d1b) * 0.1767766952966369f;

            const float mnew = fmaxf(m, fmaxf(s0, s1));
            const float corr = __expf(m - mnew);
            const float p0   = __expf(s0 - mnew);
            const float p1   = __expf(s1 - mnew);
            m = mnew;
            l = fmaf(l, corr, p0 + p1);
#pragma unroll
            for (int c = 0; c < 8; ++c) {
                float4 v0 = *(const float4*)&v_lds[ka_row][c * 4];
                float4 v1 = *(const float4*)&v_lds[kb_row][c * 4];
                acc[c*4+0] = fmaf(acc[c*4+0], corr, fmaf(p0, v0.x, p1 * v1.x));
                acc[c*4+1] = fmaf(acc[c*4+1], corr, fmaf(p0, v0.y, p1 * v1.y));
                acc[c*4+2] = fmaf(acc[c*4+2], corr, fmaf(p0, v0.z, p1 * v1.z));
                acc[c*4+3] = fmaf(acc[c*4+3], corr, fmaf(p0, v0.w, p1 * v1.w));
            }
        }
    }

    // Merge across the 8 lanes sharing this query (lanes kl=0..7, same wave)
    float mg = m;
    mg = fmaxf(mg, __shfl_xor(mg, 1));
    mg = fmaxf(mg, __shfl_xor(mg, 2));
    mg = fmaxf(mg, __shfl_xor(mg, 4));
    const float f = __expf(m - mg);
    float lt = l * f;
    lt += __shfl_xor(lt, 1);
    lt += __shfl_xor(lt, 2);
    lt += __shfl_xor(lt, 4);
#pragma unroll
    for (int c = 0; c < 32; ++c) {
        float a = acc[c] * f;
        a += __shfl_xor(a, 1);
        a += __shfl_xor(a, 2);
        a += __shfl_xor(a, 4);
        acc[c] = a;
    }
    if (kl == 0) {
        const float inv = 1.f / lt;
        float* orow = outp + base + (size_t)q * D_MODEL;
#pragma unroll
        for (int c = 0; c < 8; ++c) {
            float4 o;
            o.x = acc[c*4+0] * inv; o.y = acc[c*4+1] * inv;
            o.z = acc[c*4+2] * inv; o.w = acc[c*4+3] * inv;
            ((float4*)orow)[c] = o;
        }
    }
}

// ---------------------------------------------------------------------------
// Fused residual + LayerNorm: out_row = LN(x_row + t2_row) * g + b
// One block (256 threads) per row of 256. In-place safe (x == outp).
// ---------------------------------------------------------------------------
__global__ __launch_bounds__(256) void residual_ln_kernel(const float* __restrict__ x,
                                                          const float* __restrict__ t2,
                                                          const float* __restrict__ g,
                                                          const float* __restrict__ bt,
                                                          float* __restrict__ outp)
{
    const int row = blockIdx.x;
    const int c = threadIdx.x;
    const size_t idx = (size_t)row * D_MODEL + c;
    float v = x[idx] + t2[idx];

    float s = v, s2 = v * v;
#pragma unroll
    for (int off = 32; off; off >>= 1) {
        s  += __shfl_xor(s,  off);
        s2 += __shfl_xor(s2, off);
    }
    __shared__ float ws[4], ws2[4];
    const int wid = c >> 6;
    if ((c & 63) == 0) { ws[wid] = s; ws2[wid] = s2; }
    __syncthreads();
    const float tot  = ws[0] + ws[1] + ws[2] + ws[3];
    const float tot2 = ws2[0] + ws2[1] + ws2[2] + ws2[3];
    const float mu  = tot * (1.f / 256.f);
    const float var = tot2 * (1.f / 256.f) - mu * mu;
    outp[idx] = (v - mu) * rsqrtf(var + 1e-5f) * g[c] + bt[c];
}

// ---------------------------------------------------------------------------
// Softmax over 16 elements per row (attention weights). One thread per row.
// ---------------------------------------------------------------------------
__global__ __launch_bounds__(256) void softmax16_kernel(float* __restrict__ aw, int rows)
{
    int r = blockIdx.x * 256 + threadIdx.x;
    if (r >= rows) return;
    float* p = aw + (size_t)r * 16;
    float v[16];
    float mx = -1e30f;
#pragma unroll
    for (int i = 0; i < 16; ++i) { v[i] = p[i]; mx = fmaxf(mx, v[i]); }
    float sum = 0.f;
#pragma unroll
    for (int i = 0; i < 16; ++i) { v[i] = __expf(v[i] - mx); sum += v[i]; }
    const float inv = 1.f / sum;
#pragma unroll
    for (int i = 0; i < 16; ++i) p[i] = v[i] * inv;
}

// ---------------------------------------------------------------------------
// Deformable sampling. Block per (b,q); thread = (head h = tid>>5, chan c = tid&31).
// value: (B, S_TOTAL, NHEAD, HDIM); off: (B*NQ, 256) as (h,l,p,2);
// aw (post-softmax): (B*NQ, 128) as (h,l,p); ref: (B, NQ, 4, 2).
// ---------------------------------------------------------------------------
__global__ __launch_bounds__(256) void sample_kernel(const float* __restrict__ value,
                                                     const float* __restrict__ off,
                                                     const float* __restrict__ aw,
                                                     const float* __restrict__ ref,
                                                     float* __restrict__ outp)
{
    const int bq = blockIdx.x;              // b*NQ + q
    const int b  = bq / NQ;
    const int h  = threadIdx.x >> 5;
    const int c  = threadIdx.x & 31;

    const float* offrow = off + (size_t)bq * 256 + h * 32;   // (l,p,2): l*8+p*2
    const float* awrow  = aw  + (size_t)bq * 128 + h * 16;   // (l,p):   l*4+p
    const float* refrow = ref + (size_t)bq * 8;              // (l,2)

    const int   HL[4] = {64, 32, 16, 8};
    const int   WLv[4] = {64, 32, 16, 8};
    const int   S0[4] = {0, 4096, 5120, 5376};

    float acc = 0.f;
#pragma unroll
    for (int l = 0; l < 4; ++l) {
        const int Hl = HL[l], Wl = WLv[l];
        const float rx = refrow[l * 2 + 0];
        const float ry = refrow[l * 2 + 1];
        const size_t lvl_base = ((size_t)b * S_TOTAL + S0[l]);
#pragma unroll
        for (int p = 0; p < 4; ++p) {
            const float ox = offrow[l * 8 + p * 2 + 0];
            const float oy = offrow[l * 8 + p * 2 + 1];
            const float w  = awrow[l * 4 + p];
            const float locx = rx + ox / (float)Wl;
            const float locy = ry + oy / (float)Hl;
            const float x = locx * (float)Wl - 0.5f;
            const float y = locy * (float)Hl - 0.5f;
            const float x0f = floorf(x), y0f = floorf(y);
            const float wx1 = x - x0f, wy1 = y - y0f;
            const int x0 = (int)x0f, y0 = (int)y0f;
#pragma unroll
            for (int dy = 0; dy < 2; ++dy) {
                const int yi = y0 + dy;
                const float wy = dy ? wy1 : (1.f - wy1);
                const bool vy = (yi >= 0) && (yi <= Hl - 1);
                const int yc = min(max(yi, 0), Hl - 1);
#pragma unroll
                for (int dx = 0; dx < 2; ++dx) {
                    const int xi = x0 + dx;
                    const float wx = dx ? wx1 : (1.f - wx1);
                    const bool vx = (xi >= 0) && (xi <= Wl - 1);
                    const int xc = min(max(xi, 0), Wl - 1);
                    const float g = value[((lvl_base + (size_t)yc * Wl + xc) * NHEAD + h) * HDIM + c];
                    acc += (vx && vy) ? g * (wx * wy * w) : 0.f;
                }
            }
        }
    }
    outp[(size_t)bq * D_MODEL + h * 32 + c] = acc;
}

// ---------------------------------------------------------------------------
// Host-side orchestration
// ---------------------------------------------------------------------------
extern "C" void kernel_launch(void* const* d_in, const int* in_sizes, int n_in,
                              void* d_out, int out_size, void* d_ws, size_t ws_size,
                              hipStream_t stream)
{
    const float* tgt  = (const float*)d_in[0];
    const float* qpos = (const float*)d_in[1];
    const float* refp = (const float*)d_in[2];
    const float* src  = (const float*)d_in[3];

    // Workspace carve-up (floats)
    float* bufA  = (float*)d_ws;               // 819200
    float* bufB1 = bufA  + ROW_ELEMS;          // 819200
    float* bufB2 = bufB1 + ROW_ELEMS;          // 819200
    float* bufB3 = bufB2 + ROW_ELEMS;          // 819200
    float* bufV  = bufB3 + ROW_ELEMS;          // 2785280 (value proj)
    float* bufF  = bufV  + (size_t)M_V * D_MODEL;  // 3276800 (ffn hidden)

    float* out = (float*)d_out;

    // out = tgt
    hipMemcpyAsync(out, tgt, sizeof(float) * ROW_ELEMS, hipMemcpyDeviceToDevice, stream);

    const dim3 gQ(M_Q / 64, D_MODEL / 64);     // (50, 4)
    const dim3 gV(M_V / 64, D_MODEL / 64);     // (170, 4)
    const dim3 gAw(M_Q / 64, 128 / 64);        // (50, 2)
    const dim3 gF1(M_Q / 64, D_FFN / 64);      // (50, 16)
    const dim3 gAttn(BATCH * NHEAD, NQ / AQT); // (16, 50)

    for (int l = 0; l < NUM_LAYERS; ++l) {
        const float* sa_w_q  = (const float*)d_in[4]  + (size_t)l * 65536;
        const float* sa_b_q  = (const float*)d_in[5]  + (size_t)l * 256;
        const float* sa_w_k  = (const float*)d_in[6]  + (size_t)l * 65536;
        const float* sa_b_k  = (const float*)d_in[7]  + (size_t)l * 256;
        const float* sa_w_v  = (const float*)d_in[8]  + (size_t)l * 65536;
        const float* sa_b_v  = (const float*)d_in[9]  + (size_t)l * 256;
        const float* sa_w_o  = (const float*)d_in[10] + (size_t)l * 65536;
        const float* sa_b_o  = (const float*)d_in[11] + (size_t)l * 256;
        const float* ln2_g   = (const float*)d_in[12] + (size_t)l * 256;
        const float* ln2_b   = (const float*)d_in[13] + (size_t)l * 256;
        const float* ca_w_off  = (const float*)d_in[14] + (size_t)l * 65536;
        const float* ca_b_off  = (const float*)d_in[15] + (size_t)l * 256;
        const float* ca_w_attn = (const float*)d_in[16] + (size_t)l * 32768;
        const float* ca_b_attn = (const float*)d_in[17] + (size_t)l * 128;
        const float* ca_w_val  = (const float*)d_in[18] + (size_t)l * 65536;
        const float* ca_b_val  = (const float*)d_in[19] + (size_t)l * 256;
        const float* ca_w_out  = (const float*)d_in[20] + (size_t)l * 65536;
        const float* ca_b_out  = (const float*)d_in[21] + (size_t)l * 256;
        const float* ln1_g   = (const float*)d_in[22] + (size_t)l * 256;
        const float* ln1_b   = (const float*)d_in[23] + (size_t)l * 256;
        const float* ffn_w1  = (const float*)d_in[24] + (size_t)l * 262144;
        const float* ffn_b1  = (const float*)d_in[25] + (size_t)l * 1024;
        const float* ffn_w2  = (const float*)d_in[26] + (size_t)l * 262144;
        const float* ffn_b2  = (const float*)d_in[27] + (size_t)l * 256;
        const float* ln3_g   = (const float*)d_in[28] + (size_t)l * 256;
        const float* ln3_b   = (const float*)d_in[29] + (size_t)l * 256;

        // ---- Self-attention ----
        add_kernel<<<800, 256, 0, stream>>>(out, qpos, bufA, (int)(ROW_ELEMS / 4));
        gemm_bias<0><<<gQ, 256, 0, stream>>>(bufA, sa_w_q, sa_b_q, bufB1, M_Q, 256, 256);
        gemm_bias<0><<<gQ, 256, 0, stream>>>(bufA, sa_w_k, sa_b_k, bufB2, M_Q, 256, 256);
        gemm_bias<0><<<gQ, 256, 0, stream>>>(out,  sa_w_v, sa_b_v, bufB3, M_Q, 256, 256);
        attn_kernel<<<gAttn, 256, 0, stream>>>(bufB1, bufB2, bufB3, bufA);
        gemm_bias<0><<<gQ, 256, 0, stream>>>(bufA, sa_w_o, sa_b_o, bufB1, M_Q, 256, 256);
        residual_ln_kernel<<<M_Q, 256, 0, stream>>>(out, bufB1, ln2_g, ln2_b, out);

        // ---- Deformable cross-attention ----
        add_kernel<<<800, 256, 0, stream>>>(out, qpos, bufA, (int)(ROW_ELEMS / 4));
        gemm_bias<0><<<gV, 256, 0, stream>>>(src, ca_w_val, ca_b_val, bufV, M_V, 256, 256);
        gemm_bias<0><<<gQ, 256, 0, stream>>>(bufA, ca_w_off, ca_b_off, bufB1, M_Q, 256, 256);
        gemm_bias<0><<<gAw, 256, 0, stream>>>(bufA, ca_w_attn, ca_b_attn, bufB2, M_Q, 128, 256);
        softmax16_kernel<<<(M_Q * NHEAD + 255) / 256, 256, 0, stream>>>(bufB2, M_Q * NHEAD);
        sample_kernel<<<M_Q, 256, 0, stream>>>(bufV, bufB1, bufB2, refp, bufB3);
        gemm_bias<0><<<gQ, 256, 0, stream>>>(bufB3, ca_w_out, ca_b_out, bufA, M_Q, 256, 256);
        residual_ln_kernel<<<M_Q, 256, 0, stream>>>(out, bufA, ln1_g, ln1_b, out);

        // ---- FFN ----
        gemm_bias<1><<<gF1, 256, 0, stream>>>(out, ffn_w1, ffn_b1, bufF, M_Q, D_FFN, 256);
        gemm_bias<0><<<gQ, 256, 0, stream>>>(bufF, ffn_w2, ffn_b2, bufA, M_Q, 256, D_FFN);
        residual_ln_kernel<<<M_Q, 256, 0, stream>>>(out, bufA, ln3_g, ln3_b, out);
    }

    (void)in_sizes; (void)n_in; (void)out_size; (void)ws_size;
}

// Round 3
// 2137.942 us; speedup vs baseline: 4.2143x; 1.5047x over previous
//
#include <hip/hip_runtime.h>

// Problem constants (fixed by the reference)
#define D_MODEL   256
#define NQ        1600
#define BATCH     2
#define NHEAD     8
#define HDIM      32
#define S_TOTAL   5440
#define D_FFN     1024
#define NUM_LAYERS 6

#define M_Q   (BATCH * NQ)       // 3200
#define M_V   (BATCH * S_TOTAL)  // 10880
#define ROW_ELEMS ((size_t)M_Q * D_MODEL)   // 819200

using short8  = __attribute__((ext_vector_type(8))) short;
using floatx4 = __attribute__((ext_vector_type(4))) float;

__device__ __forceinline__ ushort f2bf(float f) {
    union { float f; unsigned u; } x; x.f = f;
    unsigned r = (x.u + 0x7fffu + ((x.u >> 16) & 1u)) >> 16;
    return (ushort)r;
}

// ---------------------------------------------------------------------------
// bf16 MFMA GEMM: C[M,N] = A[M,K](bf16) @ W[N,K](bf16)^T + bias[N], fp32 acc.
// Block tile 64x64, BK=32, 4 waves, wave = 32x32 quadrant via 2x2 MFMAs.
// OUTMODE 0: fp32 out.  OUTMODE 1: relu + bf16 out.
// Requires M%64==0, N%64==0, K%32==0 (true at all call sites).
// ---------------------------------------------------------------------------
template <int OUTMODE>
__global__ __launch_bounds__(256) void gemm_bf16(const ushort* __restrict__ A,
                                                 const ushort* __restrict__ W,
                                                 const float* __restrict__ bias,
                                                 void* __restrict__ Cout,
                                                 int M, int N, int K)
{
    __shared__ ushort Al[64][40];   // row stride 80B: 16B-aligned, <=2-way bank alias
    __shared__ ushort Bl[64][40];
    const int tid  = threadIdx.x;
    const int bm   = blockIdx.x * 64;
    const int bn   = blockIdx.y * 64;
    const int lr   = tid >> 2;          // 0..63 staging row
    const int lc   = tid & 3;           // 0..3 staging 8-elem chunk
    const int wave = tid >> 6;
    const int lane = tid & 63;
    const int mo   = (wave & 1) * 32;
    const int no   = (wave >> 1) * 32;
    const int row16 = lane & 15;
    const int quad  = lane >> 4;

    floatx4 acc[2][2] = {};

    const ushort* aG = A + (size_t)(bm + lr) * K + lc * 8;
    const ushort* wG = W + (size_t)(bn + lr) * K + lc * 8;

    for (int k0 = 0; k0 < K; k0 += 32) {
        __syncthreads();
        *(short8*)&Al[lr][lc * 8] = *(const short8*)(aG + k0);
        *(short8*)&Bl[lr][lc * 8] = *(const short8*)(wG + k0);
        __syncthreads();
        short8 af0 = *(const short8*)&Al[mo + row16][quad * 8];
        short8 af1 = *(const short8*)&Al[mo + 16 + row16][quad * 8];
        short8 bf0 = *(const short8*)&Bl[no + row16][quad * 8];
        short8 bf1 = *(const short8*)&Bl[no + 16 + row16][quad * 8];
        acc[0][0] = __builtin_amdgcn_mfma_f32_16x16x32_bf16(af0, bf0, acc[0][0], 0, 0, 0);
        acc[0][1] = __builtin_amdgcn_mfma_f32_16x16x32_bf16(af0, bf1, acc[0][1], 0, 0, 0);
        acc[1][0] = __builtin_amdgcn_mfma_f32_16x16x32_bf16(af1, bf0, acc[1][0], 0, 0, 0);
        acc[1][1] = __builtin_amdgcn_mfma_f32_16x16x32_bf16(af1, bf1, acc[1][1], 0, 0, 0);
    }

#pragma unroll
    for (int mi = 0; mi < 2; ++mi)
#pragma unroll
        for (int ni = 0; ni < 2; ++ni) {
            const int col = bn + no + ni * 16 + row16;
            const float bv = bias[col];
#pragma unroll
            for (int r = 0; r < 4; ++r) {
                const int row = bm + mo + mi * 16 + quad * 4 + r;
                float v = acc[mi][ni][r] + bv;
                if (OUTMODE == 1)
                    ((ushort*)Cout)[(size_t)row * N + col] = f2bf(fmaxf(v, 0.f));
                else
                    ((float*)Cout)[(size_t)row * N + col] = v;
            }
        }
}

// ---------------------------------------------------------------------------
// Segmented fp32 -> bf16 conversion (weights + src), one launch.
// ---------------------------------------------------------------------------
struct CvtSeg { const float* in; ushort* out; int n4; };
struct CvtArgs { CvtSeg seg[11]; };

__global__ __launch_bounds__(256) void convert_kernel(CvtArgs args)
{
    const CvtSeg sg = args.seg[blockIdx.y];
    const int i = blockIdx.x * 256 + threadIdx.x;
    if (i < sg.n4) {
        float4 v = ((const float4*)sg.in)[i];
        ushort4 o;
        o.x = f2bf(v.x); o.y = f2bf(v.y); o.z = f2bf(v.z); o.w = f2bf(v.w);
        ((ushort4*)sg.out)[i] = o;
    }
}

// out = tgt (fp32) and bf16 copy
__global__ __launch_bounds__(256) void init_out_kernel(const float* __restrict__ tgt,
                                                       float* __restrict__ out,
                                                       ushort* __restrict__ out_h, int n4)
{
    const int i = blockIdx.x * 256 + threadIdx.x;
    if (i < n4) {
        float4 v = ((const float4*)tgt)[i];
        ((float4*)out)[i] = v;
        ushort4 o;
        o.x = f2bf(v.x); o.y = f2bf(v.y); o.z = f2bf(v.z); o.w = f2bf(v.w);
        ((ushort4*)out_h)[i] = o;
    }
}

// o_h = bf16(a + b)
__global__ __launch_bounds__(256) void add_bf16_kernel(const float* __restrict__ a,
                                                       const float* __restrict__ b,
                                                       ushort* __restrict__ o_h, int n4)
{
    const int i = blockIdx.x * 256 + threadIdx.x;
    if (i < n4) {
        float4 x = ((const float4*)a)[i];
        float4 y = ((const float4*)b)[i];
        ushort4 o;
        o.x = f2bf(x.x + y.x); o.y = f2bf(x.y + y.y);
        o.z = f2bf(x.z + y.z); o.w = f2bf(x.w + y.w);
        ((ushort4*)o_h)[i] = o;
    }
}

// ---------------------------------------------------------------------------
// Self-attention, block-tiled flash style (fp32 in, bf16 out).
// Grid: (B*NHEAD, NQ/32). Block: 256 threads.
// ---------------------------------------------------------------------------
#define AQT 32
#define AKT 64

__global__ __launch_bounds__(256) void attn_kernel(const float* __restrict__ qh,
                                                   const float* __restrict__ kh,
                                                   const float* __restrict__ vh,
                                                   ushort* __restrict__ outp_h)
{
    const int bh = blockIdx.x;
    const int h  = bh & (NHEAD - 1);
    const int b  = bh >> 3;
    const int t  = threadIdx.x;
    const int qi = t >> 3;          // 0..31
    const int kl = t & 7;           // 0..7
    const int q  = blockIdx.y * AQT + qi;

    const size_t base = (size_t)b * NQ * D_MODEL + (size_t)h * HDIM;

    __shared__ float k_lds[AKT][36];
    __shared__ float v_lds[AKT][36];

    float4 qv[8];
    {
        const float* qrow = qh + base + (size_t)q * D_MODEL;
#pragma unroll
        for (int i = 0; i < 8; ++i) qv[i] = ((const float4*)qrow)[i];
    }

    float m = -1e30f, l = 0.f;
    float acc[32] = {};

    const int r0 = t >> 3,         c0 = t & 7;
    const int r1 = (t + 256) >> 3, c1 = t & 7;

    for (int k0 = 0; k0 < NQ; k0 += AKT) {
        __syncthreads();
        {
            const float4 ka = ((const float4*)(kh + base + (size_t)(k0 + r0) * D_MODEL))[c0];
            const float4 kb = ((const float4*)(kh + base + (size_t)(k0 + r1) * D_MODEL))[c1];
            const float4 va = ((const float4*)(vh + base + (size_t)(k0 + r0) * D_MODEL))[c0];
            const float4 vb = ((const float4*)(vh + base + (size_t)(k0 + r1) * D_MODEL))[c1];
            *(float4*)&k_lds[r0][c0 * 4] = ka;
            *(float4*)&k_lds[r1][c1 * 4] = kb;
            *(float4*)&v_lds[r0][c0 * 4] = va;
            *(float4*)&v_lds[r1][c1 * 4] = vb;
        }
        __syncthreads();

#pragma unroll
        for (int kk = 0; kk < 4; ++kk) {
            const int ka_row = kk * 16 + kl;
            const int kb_row = kk * 16 + 8 + kl;
            float d0a = 0.f, d0b = 0.f, d1a = 0.f, d1b = 0.f;
#pragma unroll
            for (int c = 0; c < 8; c += 2) {
                float4 x0 = *(const float4*)&k_lds[ka_row][c * 4];
                float4 x1 = *(const float4*)&k_lds[ka_row][c * 4 + 4];
                float4 y0 = *(const float4*)&k_lds[kb_row][c * 4];
                float4 y1 = *(const float4*)&k_lds[kb_row][c * 4 + 4];
                d0a = fmaf(x0.x, qv[c].x, d0a);   d0a = fmaf(x0.y, qv[c].y, d0a);
                d0a = fmaf(x0.z, qv[c].z, d0a);   d0a = fmaf(x0.w, qv[c].w, d0a);
                d0b = fmaf(x1.x, qv[c+1].x, d0b); d0b = fmaf(x1.y, qv[c+1].y, d0b);
                d0b = fmaf(x1.z, qv[c+1].z, d0b); d0b = fmaf(x1.w, qv[c+1].w, d0b);
                d1a = fmaf(y0.x, qv[c].x, d1a);   d1a = fmaf(y0.y, qv[c].y, d1a);
                d1a = fmaf(y0.z, qv[c].z, d1a);   d1a = fmaf(y0.w, qv[c].w, d1a);
                d1b = fmaf(y1.x, qv[c+1].x, d1b); d1b = fmaf(y1.y, qv[c+1].y, d1b);
                d1b = fmaf(y1.z, qv[c+1].z, d1b); d1b = fmaf(y1.w, qv[c+1].w, d1b);
            }
            const float s0 = (d0a + d0b) * 0.1767766952966369f;
            const float s1 = (d1a + d1b) * 0.1767766952966369f;

            const float mnew = fmaxf(m, fmaxf(s0, s1));
            const float corr = __expf(m - mnew);
            const float p0   = __expf(s0 - mnew);
            const float p1   = __expf(s1 - mnew);
            m = mnew;
            l = fmaf(l, corr, p0 + p1);
#pragma unroll
            for (int c = 0; c < 8; ++c) {
                float4 v0 = *(const float4*)&v_lds[ka_row][c * 4];
                float4 v1 = *(const float4*)&v_lds[kb_row][c * 4];
                acc[c*4+0] = fmaf(acc[c*4+0], corr, fmaf(p0, v0.x, p1 * v1.x));
                acc[c*4+1] = fmaf(acc[c*4+1], corr, fmaf(p0, v0.y, p1 * v1.y));
                acc[c*4+2] = fmaf(acc[c*4+2], corr, fmaf(p0, v0.z, p1 * v1.z));
                acc[c*4+3] = fmaf(acc[c*4+3], corr, fmaf(p0, v0.w, p1 * v1.w));
            }
        }
    }

    float mg = m;
    mg = fmaxf(mg, __shfl_xor(mg, 1));
    mg = fmaxf(mg, __shfl_xor(mg, 2));
    mg = fmaxf(mg, __shfl_xor(mg, 4));
    const float f = __expf(m - mg);
    float lt = l * f;
    lt += __shfl_xor(lt, 1);
    lt += __shfl_xor(lt, 2);
    lt += __shfl_xor(lt, 4);
#pragma unroll
    for (int c = 0; c < 32; ++c) {
        float a = acc[c] * f;
        a += __shfl_xor(a, 1);
        a += __shfl_xor(a, 2);
        a += __shfl_xor(a, 4);
        acc[c] = a;
    }
    if (kl == 0) {
        const float inv = 1.f / lt;
        ushort* orow = outp_h + base + (size_t)q * D_MODEL;
#pragma unroll
        for (int c = 0; c < 32; ++c) orow[c] = f2bf(acc[c] * inv);
    }
}

// ---------------------------------------------------------------------------
// Fused residual + LayerNorm -> fp32 out + bf16 out_h. In-place safe.
// ---------------------------------------------------------------------------
__global__ __launch_bounds__(256) void residual_ln_kernel(const float* __restrict__ x,
                                                          const float* __restrict__ t2,
                                                          const float* __restrict__ g,
                                                          const float* __restrict__ bt,
                                                          float* __restrict__ outp,
                                                          ushort* __restrict__ outp_h)
{
    const int row = blockIdx.x;
    const int c = threadIdx.x;
    const size_t idx = (size_t)row * D_MODEL + c;
    float v = x[idx] + t2[idx];

    float s = v, s2 = v * v;
#pragma unroll
    for (int off = 32; off; off >>= 1) {
        s  += __shfl_xor(s,  off);
        s2 += __shfl_xor(s2, off);
    }
    __shared__ float ws[4], ws2[4];
    const int wid = c >> 6;
    if ((c & 63) == 0) { ws[wid] = s; ws2[wid] = s2; }
    __syncthreads();
    const float tot  = ws[0] + ws[1] + ws[2] + ws[3];
    const float tot2 = ws2[0] + ws2[1] + ws2[2] + ws2[3];
    const float mu  = tot * (1.f / 256.f);
    const float var = tot2 * (1.f / 256.f) - mu * mu;
    const float r = (v - mu) * rsqrtf(var + 1e-5f) * g[c] + bt[c];
    outp[idx] = r;
    outp_h[idx] = f2bf(r);
}

// ---------------------------------------------------------------------------
// Softmax over 16 elements per row (attention weights). One thread per row.
// ---------------------------------------------------------------------------
__global__ __launch_bounds__(256) void softmax16_kernel(float* __restrict__ aw, int rows)
{
    int r = blockIdx.x * 256 + threadIdx.x;
    if (r >= rows) return;
    float* p = aw + (size_t)r * 16;
    float v[16];
    float mx = -1e30f;
#pragma unroll
    for (int i = 0; i < 16; ++i) { v[i] = p[i]; mx = fmaxf(mx, v[i]); }
    float sum = 0.f;
#pragma unroll
    for (int i = 0; i < 16; ++i) { v[i] = __expf(v[i] - mx); sum += v[i]; }
    const float inv = 1.f / sum;
#pragma unroll
    for (int i = 0; i < 16; ++i) p[i] = v[i] * inv;
}

// ---------------------------------------------------------------------------
// Deformable sampling (fp32 in, bf16 out). Block per (b,q).
// ---------------------------------------------------------------------------
__global__ __launch_bounds__(256) void sample_kernel(const float* __restrict__ value,
                                                     const float* __restrict__ off,
                                                     const float* __restrict__ aw,
                                                     const float* __restrict__ ref,
                                                     ushort* __restrict__ outp_h)
{
    const int bq = blockIdx.x;
    const int b  = bq / NQ;
    const int h  = threadIdx.x >> 5;
    const int c  = threadIdx.x & 31;

    const float* offrow = off + (size_t)bq * 256 + h * 32;
    const float* awrow  = aw  + (size_t)bq * 128 + h * 16;
    const float* refrow = ref + (size_t)bq * 8;

    const int   HL[4] = {64, 32, 16, 8};
    const int   WLv[4] = {64, 32, 16, 8};
    const int   S0[4] = {0, 4096, 5120, 5376};

    float acc = 0.f;
#pragma unroll
    for (int l = 0; l < 4; ++l) {
        const int Hl = HL[l], Wl = WLv[l];
        const float rx = refrow[l * 2 + 0];
        const float ry = refrow[l * 2 + 1];
        const size_t lvl_base = ((size_t)b * S_TOTAL + S0[l]);
#pragma unroll
        for (int p = 0; p < 4; ++p) {
            const float ox = offrow[l * 8 + p * 2 + 0];
            const float oy = offrow[l * 8 + p * 2 + 1];
            const float w  = awrow[l * 4 + p];
            const float locx = rx + ox / (float)Wl;
            const float locy = ry + oy / (float)Hl;
            const float x = locx * (float)Wl - 0.5f;
            const float y = locy * (float)Hl - 0.5f;
            const float x0f = floorf(x), y0f = floorf(y);
            const float wx1 = x - x0f, wy1 = y - y0f;
            const int x0 = (int)x0f, y0 = (int)y0f;
#pragma unroll
            for (int dy = 0; dy < 2; ++dy) {
                const int yi = y0 + dy;
                const float wy = dy ? wy1 : (1.f - wy1);
                const bool vy = (yi >= 0) && (yi <= Hl - 1);
                const int yc = min(max(yi, 0), Hl - 1);
#pragma unroll
                for (int dx = 0; dx < 2; ++dx) {
                    const int xi = x0 + dx;
                    const float wx = dx ? wx1 : (1.f - wx1);
                    const bool vx = (xi >= 0) && (xi <= Wl - 1);
                    const int xc = min(max(xi, 0), Wl - 1);
                    const float g = value[((lvl_base + (size_t)yc * Wl + xc) * NHEAD + h) * HDIM + c];
                    acc += (vx && vy) ? g * (wx * wy * w) : 0.f;
                }
            }
        }
    }
    outp_h[(size_t)bq * D_MODEL + h * 32 + c] = f2bf(acc);
}

// ---------------------------------------------------------------------------
// Host-side orchestration
// ---------------------------------------------------------------------------
extern "C" void kernel_launch(void* const* d_in, const int* in_sizes, int n_in,
                              void* d_out, int out_size, void* d_ws, size_t ws_size,
                              hipStream_t stream)
{
    const float* tgt  = (const float*)d_in[0];
    const float* qpos = (const float*)d_in[1];
    const float* refp = (const float*)d_in[2];
    const float* src  = (const float*)d_in[3];

    // ---- workspace carve-up ----
    float* bufQ  = (float*)d_ws;                    // 819200 (also reused as GEMM out bufT)
    float* bufK  = bufQ  + ROW_ELEMS;               // 819200
    float* bufVv = bufK  + ROW_ELEMS;               // 819200
    float* bufB1 = bufVv + ROW_ELEMS;               // 819200 (offsets fp32)
    float* bufB2 = bufB1 + ROW_ELEMS;               // 409600 (attn weights fp32)
    float* bufV  = bufB2 + (size_t)M_Q * 128;       // 2785280 (value proj fp32)

    ushort* out_h  = (ushort*)(bufV + (size_t)M_V * D_MODEL);  // 819200
    ushort* qadd_h = out_h  + ROW_ELEMS;            // 819200 (q=out+qpos, reused for attn-out / sample-out)
    ushort* bufF_h = qadd_h + ROW_ELEMS;            // 3276800 (ffn hidden bf16)
    ushort* src_h  = bufF_h + (size_t)M_Q * D_FFN;  // 2785280
    ushort* wpool  = src_h  + (size_t)M_V * D_MODEL;

    // bf16 weight pool (all 6 layers each)
    ushort* wq_h    = wpool;                  // 6*65536
    ushort* wk_h    = wq_h    + 393216;
    ushort* wv_h    = wk_h    + 393216;
    ushort* wo_h    = wv_h    + 393216;
    ushort* woff_h  = wo_h    + 393216;
    ushort* wattn_h = woff_h  + 393216;       // 6*32768
    ushort* wval_h  = wattn_h + 196608;
    ushort* wout_h  = wval_h  + 393216;
    ushort* w1_h    = wout_h  + 393216;       // 6*262144
    ushort* w2_h    = w1_h    + 1572864;

    float* out = (float*)d_out;

    // ---- one-shot conversions (weights + src), every call ----
    CvtArgs ca;
    ca.seg[0]  = { src,                       src_h,   (int)((size_t)M_V * D_MODEL / 4) };
    ca.seg[1]  = { (const float*)d_in[4],     wq_h,    393216 / 4 };
    ca.seg[2]  = { (const float*)d_in[6],     wk_h,    393216 / 4 };
    ca.seg[3]  = { (const float*)d_in[8],     wv_h,    393216 / 4 };
    ca.seg[4]  = { (const float*)d_in[10],    wo_h,    393216 / 4 };
    ca.seg[5]  = { (const float*)d_in[14],    woff_h,  393216 / 4 };
    ca.seg[6]  = { (const float*)d_in[16],    wattn_h, 196608 / 4 };
    ca.seg[7]  = { (const float*)d_in[18],    wval_h,  393216 / 4 };
    ca.seg[8]  = { (const float*)d_in[20],    wout_h,  393216 / 4 };
    ca.seg[9]  = { (const float*)d_in[24],    w1_h,    1572864 / 4 };
    ca.seg[10] = { (const float*)d_in[26],    w2_h,    1572864 / 4 };
    convert_kernel<<<dim3(2720, 11), 256, 0, stream>>>(ca);

    init_out_kernel<<<800, 256, 0, stream>>>(tgt, out, out_h, (int)(ROW_ELEMS / 4));

    const dim3 gQ(M_Q / 64, D_MODEL / 64);     // (50, 4)
    const dim3 gV(M_V / 64, D_MODEL / 64);     // (170, 4)
    const dim3 gAw(M_Q / 64, 128 / 64);        // (50, 2)
    const dim3 gF1(M_Q / 64, D_FFN / 64);      // (50, 16)
    const dim3 gAttn(BATCH * NHEAD, NQ / AQT); // (16, 50)

    for (int l = 0; l < NUM_LAYERS; ++l) {
        const float* sa_b_q  = (const float*)d_in[5]  + (size_t)l * 256;
        const float* sa_b_k  = (const float*)d_in[7]  + (size_t)l * 256;
        const float* sa_b_v  = (const float*)d_in[9]  + (size_t)l * 256;
        const float* sa_b_o  = (const float*)d_in[11] + (size_t)l * 256;
        const float* ln2_g   = (const float*)d_in[12] + (size_t)l * 256;
        const float* ln2_b   = (const float*)d_in[13] + (size_t)l * 256;
        const float* ca_b_off  = (const float*)d_in[15] + (size_t)l * 256;
        const float* ca_b_attn = (const float*)d_in[17] + (size_t)l * 128;
        const float* ca_b_val  = (const float*)d_in[19] + (size_t)l * 256;
        const float* ca_b_out  = (const float*)d_in[21] + (size_t)l * 256;
        const float* ln1_g   = (const float*)d_in[22] + (size_t)l * 256;
        const float* ln1_b   = (const float*)d_in[23] + (size_t)l * 256;
        const float* ffn_b1  = (const float*)d_in[25] + (size_t)l * 1024;
        const float* ffn_b2  = (const float*)d_in[27] + (size_t)l * 256;
        const float* ln3_g   = (const float*)d_in[28] + (size_t)l * 256;
        const float* ln3_b   = (const float*)d_in[29] + (size_t)l * 256;

        const ushort* wq = wq_h    + (size_t)l * 65536;
        const ushort* wk = wk_h    + (size_t)l * 65536;
        const ushort* wv = wv_h    + (size_t)l * 65536;
        const ushort* wo = wo_h    + (size_t)l * 65536;
        const ushort* wf = woff_h  + (size_t)l * 65536;
        const ushort* wa = wattn_h + (size_t)l * 32768;
        const ushort* wl = wval_h  + (size_t)l * 65536;
        const ushort* wu = wout_h  + (size_t)l * 65536;
        const ushort* w1 = w1_h    + (size_t)l * 262144;
        const ushort* w2 = w2_h    + (size_t)l * 262144;

        // ---- Self-attention ----
        add_bf16_kernel<<<800, 256, 0, stream>>>(out, qpos, qadd_h, (int)(ROW_ELEMS / 4));
        gemm_bf16<0><<<gQ, 256, 0, stream>>>(qadd_h, wq, sa_b_q, bufQ, M_Q, 256, 256);
        gemm_bf16<0><<<gQ, 256, 0, stream>>>(qadd_h, wk, sa_b_k, bufK, M_Q, 256, 256);
        gemm_bf16<0><<<gQ, 256, 0, stream>>>(out_h, wv, sa_b_v, bufVv, M_Q, 256, 256);
        attn_kernel<<<gAttn, 256, 0, stream>>>(bufQ, bufK, bufVv, qadd_h);
        gemm_bf16<0><<<gQ, 256, 0, stream>>>(qadd_h, wo, sa_b_o, bufQ, M_Q, 256, 256);
        residual_ln_kernel<<<M_Q, 256, 0, stream>>>(out, bufQ, ln2_g, ln2_b, out, out_h);

        // ---- Deformable cross-attention ----
        add_bf16_kernel<<<800, 256, 0, stream>>>(out, qpos, qadd_h, (int)(ROW_ELEMS / 4));
        gemm_bf16<0><<<gV, 256, 0, stream>>>(src_h, wl, ca_b_val, bufV, M_V, 256, 256);
        gemm_bf16<0><<<gQ, 256, 0, stream>>>(qadd_h, wf, ca_b_off, bufB1, M_Q, 256, 256);
        gemm_bf16<0><<<gAw, 256, 0, stream>>>(qadd_h, wa, ca_b_attn, bufB2, M_Q, 128, 256);
        softmax16_kernel<<<(M_Q * NHEAD + 255) / 256, 256, 0, stream>>>(bufB2, M_Q * NHEAD);
        sample_kernel<<<M_Q, 256, 0, stream>>>(bufV, bufB1, bufB2, refp, qadd_h);
        gemm_bf16<0><<<gQ, 256, 0, stream>>>(qadd_h, wu, ca_b_out, bufQ, M_Q, 256, 256);
        residual_ln_kernel<<<M_Q, 256, 0, stream>>>(out, bufQ, ln1_g, ln1_b, out, out_h);

        // ---- FFN ----
        gemm_bf16<1><<<gF1, 256, 0, stream>>>(out_h, w1, ffn_b1, bufF_h, M_Q, D_FFN, 256);
        gemm_bf16<0><<<gQ, 256, 0, stream>>>(bufF_h, w2, ffn_b2, bufQ, M_Q, 256, D_FFN);
        residual_ln_kernel<<<M_Q, 256, 0, stream>>>(out, bufQ, ln3_g, ln3_b, out, out_h);
    }

    (void)in_sizes; (void)n_in; (void)out_size; (void)ws_size;
}

// Round 4
// 1068.425 us; speedup vs baseline: 8.4330x; 2.0010x over previous
//
#include <hip/hip_runtime.h>

// Problem constants (fixed by the reference)
#define D_MODEL   256
#define NQ        1600
#define BATCH     2
#define NHEAD     8
#define HDIM      32
#define S_TOTAL   5440
#define D_FFN     1024
#define NUM_LAYERS 6

#define M_Q   (BATCH * NQ)       // 3200
#define M_V   (BATCH * S_TOTAL)  // 10880
#define ROW_ELEMS ((size_t)M_Q * D_MODEL)   // 819200

using short8  = __attribute__((ext_vector_type(8))) short;
using floatx4 = __attribute__((ext_vector_type(4))) float;

__device__ __forceinline__ ushort f2bf(float f) {
    union { float f; unsigned u; } x; x.f = f;
    unsigned r = (x.u + 0x7fffu + ((x.u >> 16) & 1u)) >> 16;
    return (ushort)r;
}
__device__ __forceinline__ float bf2f(ushort b) {
    union { unsigned u; float f; } x; x.u = ((unsigned)b) << 16;
    return x.f;
}

// ---------------------------------------------------------------------------
// Segmented bf16 MFMA GEMM. Each bn-block (64 cols) has its own descriptor:
// C[M, seg] = A[M,K] @ W[64,K]^T, v = (acc + bias)*scale, then mode:
//   0: fp32 store (C + row*ldc + col)
//   1: relu + bf16 store
//   2: bf16 store
//   3: bf16 TRANSPOSED store into (b, ncol, q) layout: C + b*256*NQ + col*NQ + q
// Block tile 64x64, BK=32, 4 waves (2x2 16x16x32 MFMAs each).
// Requires M%64==0, K%32==0.
// ---------------------------------------------------------------------------
struct GSeg {
    const ushort* A;
    const ushort* W;      // pre-offset to this 64-col block (row 0 of block)
    const float*  bias;   // pre-offset
    void*         C;      // col-offset pre-applied (modes 0-2); col*NQ for mode 3
    int           ldc;
    int           mode;
    float         scale;
};
struct GArgs { GSeg s[16]; };

__global__ __launch_bounds__(256) void gemm_multi(GArgs args, int M, int K)
{
    const GSeg sg = args.s[blockIdx.y];
    __shared__ ushort Al[64][40];
    __shared__ ushort Bl[64][40];
    const int tid  = threadIdx.x;
    const int bm   = blockIdx.x * 64;
    const int lr   = tid >> 2;
    const int lc   = tid & 3;
    const int wave = tid >> 6;
    const int lane = tid & 63;
    const int mo   = (wave & 1) * 32;
    const int no   = (wave >> 1) * 32;
    const int row16 = lane & 15;
    const int quad  = lane >> 4;

    floatx4 acc[2][2] = {};

    const ushort* aG = sg.A + (size_t)(bm + lr) * K + lc * 8;
    const ushort* wG = sg.W + (size_t)lr * K + lc * 8;

    for (int k0 = 0; k0 < K; k0 += 32) {
        __syncthreads();
        *(short8*)&Al[lr][lc * 8] = *(const short8*)(aG + k0);
        *(short8*)&Bl[lr][lc * 8] = *(const short8*)(wG + k0);
        __syncthreads();
        short8 af0 = *(const short8*)&Al[mo + row16][quad * 8];
        short8 af1 = *(const short8*)&Al[mo + 16 + row16][quad * 8];
        short8 bf0 = *(const short8*)&Bl[no + row16][quad * 8];
        short8 bf1 = *(const short8*)&Bl[no + 16 + row16][quad * 8];
        acc[0][0] = __builtin_amdgcn_mfma_f32_16x16x32_bf16(af0, bf0, acc[0][0], 0, 0, 0);
        acc[0][1] = __builtin_amdgcn_mfma_f32_16x16x32_bf16(af0, bf1, acc[0][1], 0, 0, 0);
        acc[1][0] = __builtin_amdgcn_mfma_f32_16x16x32_bf16(af1, bf0, acc[1][0], 0, 0, 0);
        acc[1][1] = __builtin_amdgcn_mfma_f32_16x16x32_bf16(af1, bf1, acc[1][1], 0, 0, 0);
    }

#pragma unroll
    for (int mi = 0; mi < 2; ++mi)
#pragma unroll
        for (int ni = 0; ni < 2; ++ni) {
            const int col = no + ni * 16 + row16;   // local col 0..63
            const float bv = sg.bias[col];
            if (sg.mode == 3) {
                const int rowb = bm + mo + mi * 16 + quad * 4;
                const int b    = rowb / NQ;
                const int mloc = rowb - b * NQ;
                ushort4 st;
                st.x = f2bf((acc[mi][ni][0] + bv) * sg.scale);
                st.y = f2bf((acc[mi][ni][1] + bv) * sg.scale);
                st.z = f2bf((acc[mi][ni][2] + bv) * sg.scale);
                st.w = f2bf((acc[mi][ni][3] + bv) * sg.scale);
                *(ushort4*)((ushort*)sg.C + (size_t)b * (256 * NQ) + (size_t)col * NQ + mloc) = st;
            } else {
#pragma unroll
                for (int r = 0; r < 4; ++r) {
                    const int row = bm + mo + mi * 16 + quad * 4 + r;
                    float v = (acc[mi][ni][r] + bv) * sg.scale;
                    if (sg.mode == 0)
                        ((float*)sg.C)[(size_t)row * sg.ldc + col] = v;
                    else if (sg.mode == 1)
                        ((ushort*)sg.C)[(size_t)row * sg.ldc + col] = f2bf(fmaxf(v, 0.f));
                    else
                        ((ushort*)sg.C)[(size_t)row * sg.ldc + col] = f2bf(v);
                }
            }
        }
}

// ---------------------------------------------------------------------------
// MFMA flash self-attention.
// Grid (B*NHEAD, NQ/64), 256 threads = 4 waves x 16 queries.
// Q/K: (b*NQ+q)*256 + h*32 (bf16, Q pre-scaled by 1/sqrt(32)).
// Vt:  (b,h,d,q) = ((b*8+h)*32 + d)*NQ + q  (bf16, from mode-3 GEMM).
// Out: bf16, (b*NQ+q)*256 + h*32.
// ---------------------------------------------------------------------------
__global__ __launch_bounds__(256) void attn_mfma(const ushort* __restrict__ Qh,
                                                 const ushort* __restrict__ Kh,
                                                 const ushort* __restrict__ Vt,
                                                 ushort* __restrict__ Oh)
{
    const int bh = blockIdx.x;
    const int h  = bh & 7, b = bh >> 3;
    const int qbase = blockIdx.y * 64;
    const int tid  = threadIdx.x;
    const int wave = tid >> 6, lane = tid & 63;
    const int lr   = lane & 15, quad = lane >> 4;

    __shared__ ushort Kl[64][40];        // keys x dims
    __shared__ ushort Vl[32][72];        // dims x keys
    __shared__ ushort Pl[4][16][72];     // per-wave P tile (q x keys)

    const short8 qf = *(const short8*)(Qh + (size_t)(b * NQ + qbase + wave * 16 + lr) * 256 + h * 32 + quad * 8);

    float mrow[4] = {-1e30f, -1e30f, -1e30f, -1e30f};
    float lsum[4] = {0.f, 0.f, 0.f, 0.f};
    floatx4 accO[2] = {};
    const floatx4 zero = {0.f, 0.f, 0.f, 0.f};

    const int krow = tid >> 2, kchk = tid & 3;       // K staging
    const int vrow = tid >> 3, vchk = tid & 7;       // V staging
    const ushort* Kgb = Kh + (size_t)b * NQ * 256 + h * 32;
    const ushort* Vgb = Vt + (size_t)bh * 32 * NQ;

    for (int k0 = 0; k0 < NQ; k0 += 64) {
        __syncthreads();
        *(short8*)&Kl[krow][kchk * 8] = *(const short8*)(Kgb + (size_t)(k0 + krow) * 256 + kchk * 8);
        *(short8*)&Vl[vrow][vchk * 8] = *(const short8*)(Vgb + (size_t)vrow * NQ + k0 + vchk * 8);
        __syncthreads();

        floatx4 s[4];
#pragma unroll
        for (int cb = 0; cb < 4; ++cb) {
            short8 kf = *(const short8*)&Kl[cb * 16 + lr][quad * 8];
            s[cb] = __builtin_amdgcn_mfma_f32_16x16x32_bf16(qf, kf, zero, 0, 0, 0);
        }
        float corr[4];
#pragma unroll
        for (int r = 0; r < 4; ++r) {
            float mx = fmaxf(fmaxf(s[0][r], s[1][r]), fmaxf(s[2][r], s[3][r]));
            mx = fmaxf(mx, __shfl_xor(mx, 1));
            mx = fmaxf(mx, __shfl_xor(mx, 2));
            mx = fmaxf(mx, __shfl_xor(mx, 4));
            mx = fmaxf(mx, __shfl_xor(mx, 8));
            const float mnew = fmaxf(mrow[r], mx);
            corr[r] = __expf(mrow[r] - mnew);
            mrow[r] = mnew;
        }
        float rsum[4] = {0.f, 0.f, 0.f, 0.f};
#pragma unroll
        for (int cb = 0; cb < 4; ++cb)
#pragma unroll
            for (int r = 0; r < 4; ++r) {
                const float p = __expf(s[cb][r] - mrow[r]);
                s[cb][r] = p;
                rsum[r] += p;
            }
#pragma unroll
        for (int r = 0; r < 4; ++r) {
            float t = rsum[r];
            t += __shfl_xor(t, 1);
            t += __shfl_xor(t, 2);
            t += __shfl_xor(t, 4);
            t += __shfl_xor(t, 8);
            lsum[r] = lsum[r] * corr[r] + t;
            accO[0][r] *= corr[r];
            accO[1][r] *= corr[r];
        }
#pragma unroll
        for (int cb = 0; cb < 4; ++cb)
#pragma unroll
            for (int r = 0; r < 4; ++r)
                Pl[wave][quad * 4 + r][cb * 16 + lr] = f2bf(s[cb][r]);
        __syncthreads();
#pragma unroll
        for (int kc = 0; kc < 2; ++kc) {
            short8 pf = *(const short8*)&Pl[wave][lr][kc * 32 + quad * 8];
            short8 v0 = *(const short8*)&Vl[lr][kc * 32 + quad * 8];
            short8 v1 = *(const short8*)&Vl[16 + lr][kc * 32 + quad * 8];
            accO[0] = __builtin_amdgcn_mfma_f32_16x16x32_bf16(pf, v0, accO[0], 0, 0, 0);
            accO[1] = __builtin_amdgcn_mfma_f32_16x16x32_bf16(pf, v1, accO[1], 0, 0, 0);
        }
    }

    ushort* orow = Oh + (size_t)(b * NQ + qbase + wave * 16) * 256 + h * 32;
#pragma unroll
    for (int r = 0; r < 4; ++r) {
        const float inv = 1.f / lsum[r];
        const int q = quad * 4 + r;
        orow[(size_t)q * 256 + lr]      = f2bf(accO[0][r] * inv);
        orow[(size_t)q * 256 + 16 + lr] = f2bf(accO[1][r] * inv);
    }
}

// ---------------------------------------------------------------------------
// Segmented fp32 -> bf16 conversion (weights + src), one launch.
// ---------------------------------------------------------------------------
struct CvtSeg { const float* in; ushort* out; int n4; };
struct CvtArgs { CvtSeg seg[11]; };

__global__ __launch_bounds__(256) void convert_kernel(CvtArgs args)
{
    const CvtSeg sg = args.seg[blockIdx.y];
    const int i = blockIdx.x * 256 + threadIdx.x;
    if (i < sg.n4) {
        float4 v = ((const float4*)sg.in)[i];
        ushort4 o;
        o.x = f2bf(v.x); o.y = f2bf(v.y); o.z = f2bf(v.z); o.w = f2bf(v.w);
        ((ushort4*)sg.out)[i] = o;
    }
}

// out = tgt (fp32), out_h = bf16(tgt), qadd_h = bf16(tgt + qpos)
__global__ __launch_bounds__(256) void init_out_kernel(const float* __restrict__ tgt,
                                                       const float* __restrict__ qpos,
                                                       float* __restrict__ out,
                                                       ushort* __restrict__ out_h,
                                                       ushort* __restrict__ qadd_h, int n4)
{
    const int i = blockIdx.x * 256 + threadIdx.x;
    if (i < n4) {
        float4 v = ((const float4*)tgt)[i];
        float4 p = ((const float4*)qpos)[i];
        ((float4*)out)[i] = v;
        ushort4 o, qa;
        o.x = f2bf(v.x); o.y = f2bf(v.y); o.z = f2bf(v.z); o.w = f2bf(v.w);
        qa.x = f2bf(v.x + p.x); qa.y = f2bf(v.y + p.y);
        qa.z = f2bf(v.z + p.z); qa.w = f2bf(v.w + p.w);
        ((ushort4*)out_h)[i] = o;
        ((ushort4*)qadd_h)[i] = qa;
    }
}

// ---------------------------------------------------------------------------
// Fused residual + LayerNorm -> out fp32, out_h bf16, qadd_h = bf16(ln + qpos).
// One block per row. In-place safe.
// ---------------------------------------------------------------------------
__global__ __launch_bounds__(256) void residual_ln_kernel(const float* __restrict__ x,
                                                          const float* __restrict__ t2,
                                                          const float* __restrict__ g,
                                                          const float* __restrict__ bt,
                                                          const float* __restrict__ qpos,
                                                          float* __restrict__ outp,
                                                          ushort* __restrict__ outp_h,
                                                          ushort* __restrict__ qadd_h)
{
    const int row = blockIdx.x;
    const int c = threadIdx.x;
    const size_t idx = (size_t)row * D_MODEL + c;
    float v = x[idx] + t2[idx];

    float s = v, s2 = v * v;
#pragma unroll
    for (int off = 32; off; off >>= 1) {
        s  += __shfl_xor(s,  off);
        s2 += __shfl_xor(s2, off);
    }
    __shared__ float ws[4], ws2[4];
    const int wid = c >> 6;
    if ((c & 63) == 0) { ws[wid] = s; ws2[wid] = s2; }
    __syncthreads();
    const float tot  = ws[0] + ws[1] + ws[2] + ws[3];
    const float tot2 = ws2[0] + ws2[1] + ws2[2] + ws2[3];
    const float mu  = tot * (1.f / 256.f);
    const float var = tot2 * (1.f / 256.f) - mu * mu;
    const float r = (v - mu) * rsqrtf(var + 1e-5f) * g[c] + bt[c];
    outp[idx] = r;
    outp_h[idx] = f2bf(r);
    qadd_h[idx] = f2bf(r + qpos[idx]);
}

// ---------------------------------------------------------------------------
// Deformable sampling with inline softmax over the 16 attention weights.
// Block per (b,q); thread = (head h = tid>>5, chan c = tid&31).
// value (bf16): (b*S_TOTAL + s)*256 + h*32 + c. off fp32, aw (raw logits) fp32.
// ---------------------------------------------------------------------------
__global__ __launch_bounds__(256) void sample_kernel(const ushort* __restrict__ value,
                                                     const float* __restrict__ off,
                                                     const float* __restrict__ aw,
                                                     const float* __restrict__ ref,
                                                     ushort* __restrict__ outp_h)
{
    const int bq = blockIdx.x;
    const int b  = bq / NQ;
    const int h  = threadIdx.x >> 5;
    const int c  = threadIdx.x & 31;

    const float* offrow = off + (size_t)bq * 256 + h * 32;
    const float* awrow  = aw  + (size_t)bq * 128 + h * 16;
    const float* refrow = ref + (size_t)bq * 8;

    // inline softmax over 16 logits
    float w16[16];
    {
        float mx = -1e30f;
#pragma unroll
        for (int i = 0; i < 16; ++i) { w16[i] = awrow[i]; mx = fmaxf(mx, w16[i]); }
        float sum = 0.f;
#pragma unroll
        for (int i = 0; i < 16; ++i) { w16[i] = __expf(w16[i] - mx); sum += w16[i]; }
        const float inv = 1.f / sum;
#pragma unroll
        for (int i = 0; i < 16; ++i) w16[i] *= inv;
    }

    const int HL[4]  = {64, 32, 16, 8};
    const int WLv[4] = {64, 32, 16, 8};
    const int S0[4]  = {0, 4096, 5120, 5376};

    float acc = 0.f;
#pragma unroll
    for (int l = 0; l < 4; ++l) {
        const int Hl = HL[l], Wl = WLv[l];
        const float rx = refrow[l * 2 + 0];
        const float ry = refrow[l * 2 + 1];
        const size_t lvl_base = ((size_t)b * S_TOTAL + S0[l]);
#pragma unroll
        for (int p = 0; p < 4; ++p) {
            const float ox = offrow[l * 8 + p * 2 + 0];
            const float oy = offrow[l * 8 + p * 2 + 1];
            const float w  = w16[l * 4 + p];
            const float locx = rx + ox / (float)Wl;
            const float locy = ry + oy / (float)Hl;
            const float x = locx * (float)Wl - 0.5f;
            const float y = locy * (float)Hl - 0.5f;
            const float x0f = floorf(x), y0f = floorf(y);
            const float wx1 = x - x0f, wy1 = y - y0f;
            const int x0 = (int)x0f, y0 = (int)y0f;
#pragma unroll
            for (int dy = 0; dy < 2; ++dy) {
                const int yi = y0 + dy;
                const float wy = dy ? wy1 : (1.f - wy1);
                const bool vy = (yi >= 0) && (yi <= Hl - 1);
                const int yc = min(max(yi, 0), Hl - 1);
#pragma unroll
                for (int dx = 0; dx < 2; ++dx) {
                    const int xi = x0 + dx;
                    const float wx = dx ? wx1 : (1.f - wx1);
                    const bool vx = (xi >= 0) && (xi <= Wl - 1);
                    const int xc = min(max(xi, 0), Wl - 1);
                    const float g = bf2f(value[((lvl_base + (size_t)yc * Wl + xc)) * 256 + h * 32 + c]);
                    acc += (vx && vy) ? g * (wx * wy * w) : 0.f;
                }
            }
        }
    }
    outp_h[(size_t)bq * D_MODEL + h * 32 + c] = f2bf(acc);
}

// ---------------------------------------------------------------------------
// Host-side orchestration
// ---------------------------------------------------------------------------
extern "C" void kernel_launch(void* const* d_in, const int* in_sizes, int n_in,
                              void* d_out, int out_size, void* d_ws, size_t ws_size,
                              hipStream_t stream)
{
    const float* tgt  = (const float*)d_in[0];
    const float* qpos = (const float*)d_in[1];
    const float* refp = (const float*)d_in[2];
    const float* src  = (const float*)d_in[3];

    // ---- workspace carve-up ----
    float* bufT   = (float*)d_ws;                   // 819200 (GEMM fp32 out pre-LN)
    float* bufOff = bufT   + ROW_ELEMS;             // 819200
    float* bufAw  = bufOff + ROW_ELEMS;             // 409600

    ushort* out_h   = (ushort*)(bufAw + (size_t)M_Q * 128);
    ushort* qadd_h  = out_h   + ROW_ELEMS;
    ushort* bufX_h  = qadd_h  + ROW_ELEMS;          // attn-out / sample-out
    ushort* bufQh   = bufX_h  + ROW_ELEMS;
    ushort* bufKh   = bufQh   + ROW_ELEMS;
    ushort* bufVt   = bufKh   + ROW_ELEMS;          // V^T (b,h,d,q)
    ushort* bufF_h  = bufVt   + ROW_ELEMS;          // 3276800 ffn hidden
    ushort* bufVal  = bufF_h  + (size_t)M_Q * D_FFN;   // 2785280 deform value (per layer)
    ushort* src_h   = bufVal  + (size_t)M_V * D_MODEL; // 2785280
    ushort* wpool   = src_h   + (size_t)M_V * D_MODEL;

    ushort* wq_h    = wpool;
    ushort* wk_h    = wq_h    + 393216;
    ushort* wv_h    = wk_h    + 393216;
    ushort* wo_h    = wv_h    + 393216;
    ushort* woff_h  = wo_h    + 393216;
    ushort* wattn_h = woff_h  + 393216;
    ushort* wval_h  = wattn_h + 196608;
    ushort* wout_h  = wval_h  + 393216;
    ushort* w1_h    = wout_h  + 393216;
    ushort* w2_h    = w1_h    + 1572864;

    float* out = (float*)d_out;

    // ---- conversions ----
    CvtArgs ca;
    ca.seg[0]  = { src,                    src_h,   (int)((size_t)M_V * D_MODEL / 4) };
    ca.seg[1]  = { (const float*)d_in[4],  wq_h,    393216 / 4 };
    ca.seg[2]  = { (const float*)d_in[6],  wk_h,    393216 / 4 };
    ca.seg[3]  = { (const float*)d_in[8],  wv_h,    393216 / 4 };
    ca.seg[4]  = { (const float*)d_in[10], wo_h,    393216 / 4 };
    ca.seg[5]  = { (const float*)d_in[14], woff_h,  393216 / 4 };
    ca.seg[6]  = { (const float*)d_in[16], wattn_h, 196608 / 4 };
    ca.seg[7]  = { (const float*)d_in[18], wval_h,  393216 / 4 };
    ca.seg[8]  = { (const float*)d_in[20], wout_h,  393216 / 4 };
    ca.seg[9]  = { (const float*)d_in[24], w1_h,    1572864 / 4 };
    ca.seg[10] = { (const float*)d_in[26], w2_h,    1572864 / 4 };
    convert_kernel<<<dim3(2720, 11), 256, 0, stream>>>(ca);

    init_out_kernel<<<800, 256, 0, stream>>>(tgt, qpos, out, out_h, qadd_h, (int)(ROW_ELEMS / 4));

    const float QSCALE = 0.1767766952966369f;

    for (int l = 0; l < NUM_LAYERS; ++l) {
        const float* sa_b_q    = (const float*)d_in[5]  + (size_t)l * 256;
        const float* sa_b_k    = (const float*)d_in[7]  + (size_t)l * 256;
        const float* sa_b_v    = (const float*)d_in[9]  + (size_t)l * 256;
        const float* sa_b_o    = (const float*)d_in[11] + (size_t)l * 256;
        const float* ln2_g     = (const float*)d_in[12] + (size_t)l * 256;
        const float* ln2_b     = (const float*)d_in[13] + (size_t)l * 256;
        const float* ca_b_off  = (const float*)d_in[15] + (size_t)l * 256;
        const float* ca_b_attn = (const float*)d_in[17] + (size_t)l * 128;
        const float* ca_b_val  = (const float*)d_in[19] + (size_t)l * 256;
        const float* ca_b_out  = (const float*)d_in[21] + (size_t)l * 256;
        const float* ln1_g     = (const float*)d_in[22] + (size_t)l * 256;
        const float* ln1_b     = (const float*)d_in[23] + (size_t)l * 256;
        const float* ffn_b1    = (const float*)d_in[25] + (size_t)l * 1024;
        const float* ffn_b2    = (const float*)d_in[27] + (size_t)l * 256;
        const float* ln3_g     = (const float*)d_in[28] + (size_t)l * 256;
        const float* ln3_b     = (const float*)d_in[29] + (size_t)l * 256;

        const ushort* wq = wq_h    + (size_t)l * 65536;
        const ushort* wk = wk_h    + (size_t)l * 65536;
        const ushort* wv = wv_h    + (size_t)l * 65536;
        const ushort* wo = wo_h    + (size_t)l * 65536;
        const ushort* wf = woff_h  + (size_t)l * 65536;
        const ushort* wa = wattn_h + (size_t)l * 32768;
        const ushort* wl = wval_h  + (size_t)l * 65536;
        const ushort* wu = wout_h  + (size_t)l * 65536;
        const ushort* w1 = w1_h    + (size_t)l * 262144;
        const ushort* w2 = w2_h    + (size_t)l * 262144;

        GArgs ga;

        // ---- QKV projections (one dispatch, 12 bn-blocks) ----
        for (int i = 0; i < 4; ++i) {
            ga.s[i]     = { qadd_h, wq + (size_t)i * 64 * 256, sa_b_q + i * 64, bufQh + i * 64, 256, 2, QSCALE };
            ga.s[4 + i] = { qadd_h, wk + (size_t)i * 64 * 256, sa_b_k + i * 64, bufKh + i * 64, 256, 2, 1.f };
            ga.s[8 + i] = { out_h,  wv + (size_t)i * 64 * 256, sa_b_v + i * 64, bufVt + (size_t)i * 64 * NQ, 256, 3, 1.f };
        }
        gemm_multi<<<dim3(M_Q / 64, 12), 256, 0, stream>>>(ga, M_Q, 256);

        attn_mfma<<<dim3(16, NQ / 64), 256, 0, stream>>>(bufQh, bufKh, bufVt, bufX_h);

        for (int i = 0; i < 4; ++i)
            ga.s[i] = { bufX_h, wo + (size_t)i * 64 * 256, sa_b_o + i * 64, bufT + i * 64, 256, 0, 1.f };
        gemm_multi<<<dim3(M_Q / 64, 4), 256, 0, stream>>>(ga, M_Q, 256);

        residual_ln_kernel<<<M_Q, 256, 0, stream>>>(out, bufT, ln2_g, ln2_b, qpos, out, out_h, qadd_h);

        // ---- Deformable cross-attention ----
        for (int i = 0; i < 4; ++i)
            ga.s[i] = { qadd_h, wf + (size_t)i * 64 * 256, ca_b_off + i * 64, bufOff + i * 64, 256, 0, 1.f };
        for (int i = 0; i < 2; ++i)
            ga.s[4 + i] = { qadd_h, wa + (size_t)i * 64 * 256, ca_b_attn + i * 64, bufAw + i * 64, 128, 0, 1.f };
        gemm_multi<<<dim3(M_Q / 64, 6), 256, 0, stream>>>(ga, M_Q, 256);

        for (int i = 0; i < 4; ++i)
            ga.s[i] = { src_h, wl + (size_t)i * 64 * 256, ca_b_val + i * 64, bufVal + i * 64, 256, 2, 1.f };
        gemm_multi<<<dim3(M_V / 64, 4), 256, 0, stream>>>(ga, M_V, 256);

        sample_kernel<<<M_Q, 256, 0, stream>>>(bufVal, bufOff, bufAw, refp, bufX_h);

        for (int i = 0; i < 4; ++i)
            ga.s[i] = { bufX_h, wu + (size_t)i * 64 * 256, ca_b_out + i * 64, bufT + i * 64, 256, 0, 1.f };
        gemm_multi<<<dim3(M_Q / 64, 4), 256, 0, stream>>>(ga, M_Q, 256);

        residual_ln_kernel<<<M_Q, 256, 0, stream>>>(out, bufT, ln1_g, ln1_b, qpos, out, out_h, qadd_h);

        // ---- FFN ----
        for (int i = 0; i < 16; ++i)
            ga.s[i] = { out_h, w1 + (size_t)i * 64 * 256, ffn_b1 + i * 64, bufF_h + i * 64, 1024, 1, 1.f };
        gemm_multi<<<dim3(M_Q / 64, 16), 256, 0, stream>>>(ga, M_Q, 256);

        for (int i = 0; i < 4; ++i)
            ga.s[i] = { bufF_h, w2 + (size_t)i * 64 * 1024, ffn_b2 + i * 64, bufT + i * 64, 256, 0, 1.f };
        gemm_multi<<<dim3(M_Q / 64, 4), 256, 0, stream>>>(ga, M_Q, 1024);

        residual_ln_kernel<<<M_Q, 256, 0, stream>>>(out, bufT, ln3_g, ln3_b, qpos, out, out_h, qadd_h);
    }

    (void)in_sizes; (void)n_in; (void)out_size; (void)ws_size;
}

// Round 5
// 1050.597 us; speedup vs baseline: 8.5761x; 1.0170x over previous
//
#include <hip/hip_runtime.h>

// Problem constants (fixed by the reference)
#define D_MODEL   256
#define NQ        1600
#define BATCH     2
#define NHEAD     8
#define HDIM      32
#define S_TOTAL   5440
#define D_FFN     1024
#define NUM_LAYERS 6

#define M_Q   (BATCH * NQ)       // 3200
#define M_V   (BATCH * S_TOTAL)  // 10880
#define ROW_ELEMS ((size_t)M_Q * D_MODEL)   // 819200

using short8  = __attribute__((ext_vector_type(8))) short;
using floatx4 = __attribute__((ext_vector_type(4))) float;

__device__ __forceinline__ ushort f2bf(float f) {
    union { float f; unsigned u; } x; x.f = f;
    unsigned r = (x.u + 0x7fffu + ((x.u >> 16) & 1u)) >> 16;
    return (ushort)r;
}
__device__ __forceinline__ float bf2f(ushort b) {
    union { unsigned u; float f; } x; x.u = ((unsigned)b) << 16;
    return x.f;
}

// ---------------------------------------------------------------------------
// Segmented bf16 MFMA GEMM. Each bn-block (64 cols) has its own descriptor:
// C[M, seg] = A[M,K] @ W[64,K]^T, v = (acc + bias)*scale, then mode:
//   0: fp32 store (C + row*ldc + col)
//   1: relu + bf16 store
//   2: bf16 store
//   3: bf16 TRANSPOSED store into (b, ncol, q) layout: C + b*256*NQ + col*NQ + q
// mblk: number of valid 64-row blocks in M for this segment (blocks above exit).
// Block tile 64x64, BK=32, 4 waves (2x2 16x16x32 MFMAs each). K%32==0.
// ---------------------------------------------------------------------------
struct GSeg {
    const ushort* A;
    const ushort* W;      // pre-offset to this 64-col block (row 0 of block)
    const float*  bias;   // pre-offset
    void*         C;      // col-offset pre-applied (modes 0-2)
    int           ldc;
    int           mode;
    int           mblk;
    float         scale;
};
struct GArgs { GSeg s[16]; };

__global__ __launch_bounds__(256) void gemm_multi(GArgs args, int K)
{
    const GSeg sg = args.s[blockIdx.y];
    if ((int)blockIdx.x >= sg.mblk) return;
    __shared__ ushort Al[64][40];
    __shared__ ushort Bl[64][40];
    const int tid  = threadIdx.x;
    const int bm   = blockIdx.x * 64;
    const int lr   = tid >> 2;
    const int lc   = tid & 3;
    const int wave = tid >> 6;
    const int lane = tid & 63;
    const int mo   = (wave & 1) * 32;
    const int no   = (wave >> 1) * 32;
    const int row16 = lane & 15;
    const int quad  = lane >> 4;

    floatx4 acc[2][2] = {};

    const ushort* aG = sg.A + (size_t)(bm + lr) * K + lc * 8;
    const ushort* wG = sg.W + (size_t)lr * K + lc * 8;

    for (int k0 = 0; k0 < K; k0 += 32) {
        __syncthreads();
        *(short8*)&Al[lr][lc * 8] = *(const short8*)(aG + k0);
        *(short8*)&Bl[lr][lc * 8] = *(const short8*)(wG + k0);
        __syncthreads();
        short8 af0 = *(const short8*)&Al[mo + row16][quad * 8];
        short8 af1 = *(const short8*)&Al[mo + 16 + row16][quad * 8];
        short8 bf0 = *(const short8*)&Bl[no + row16][quad * 8];
        short8 bf1 = *(const short8*)&Bl[no + 16 + row16][quad * 8];
        acc[0][0] = __builtin_amdgcn_mfma_f32_16x16x32_bf16(af0, bf0, acc[0][0], 0, 0, 0);
        acc[0][1] = __builtin_amdgcn_mfma_f32_16x16x32_bf16(af0, bf1, acc[0][1], 0, 0, 0);
        acc[1][0] = __builtin_amdgcn_mfma_f32_16x16x32_bf16(af1, bf0, acc[1][0], 0, 0, 0);
        acc[1][1] = __builtin_amdgcn_mfma_f32_16x16x32_bf16(af1, bf1, acc[1][1], 0, 0, 0);
    }

#pragma unroll
    for (int mi = 0; mi < 2; ++mi)
#pragma unroll
        for (int ni = 0; ni < 2; ++ni) {
            const int col = no + ni * 16 + row16;   // local col 0..63
            const float bv = sg.bias[col];
            if (sg.mode == 3) {
                const int rowb = bm + mo + mi * 16 + quad * 4;
                const int b    = rowb / NQ;
                const int mloc = rowb - b * NQ;
                ushort4 st;
                st.x = f2bf((acc[mi][ni][0] + bv) * sg.scale);
                st.y = f2bf((acc[mi][ni][1] + bv) * sg.scale);
                st.z = f2bf((acc[mi][ni][2] + bv) * sg.scale);
                st.w = f2bf((acc[mi][ni][3] + bv) * sg.scale);
                *(ushort4*)((ushort*)sg.C + (size_t)b * (256 * NQ) + (size_t)col * NQ + mloc) = st;
            } else {
#pragma unroll
                for (int r = 0; r < 4; ++r) {
                    const int row = bm + mo + mi * 16 + quad * 4 + r;
                    float v = (acc[mi][ni][r] + bv) * sg.scale;
                    if (sg.mode == 0)
                        ((float*)sg.C)[(size_t)row * sg.ldc + col] = v;
                    else if (sg.mode == 1)
                        ((ushort*)sg.C)[(size_t)row * sg.ldc + col] = f2bf(fmaxf(v, 0.f));
                    else
                        ((ushort*)sg.C)[(size_t)row * sg.ldc + col] = f2bf(v);
                }
            }
        }
}

// ---------------------------------------------------------------------------
// Barrier-free MFMA flash self-attention.
// Grid (B*NHEAD, NQ/64), 256 threads = 4 independent waves x 16 queries.
// K and V fragments are loaded DIRECTLY from global in MFMA operand layout
// (no LDS staging, no __syncthreads). Only P uses a wave-private LDS tile
// (same-wave DS ops are in-order; no barrier needed).
// Q/K: (b*NQ+q)*256 + h*32 (bf16, Q pre-scaled by 1/sqrt(32)).
// Vt:  ((b*8+h)*32 + d)*NQ + q  (bf16, from mode-3 GEMM).
// ---------------------------------------------------------------------------
__global__ __launch_bounds__(256) void attn_mfma(const ushort* __restrict__ Qh,
                                                 const ushort* __restrict__ Kh,
                                                 const ushort* __restrict__ Vt,
                                                 ushort* __restrict__ Oh)
{
    const int bh = blockIdx.x;
    const int h  = bh & 7, b = bh >> 3;
    const int tid  = threadIdx.x;
    const int wave = tid >> 6, lane = tid & 63;
    const int lr   = lane & 15, quad = lane >> 4;
    const int q0   = blockIdx.y * 64 + wave * 16;

    __shared__ ushort Pl[4][16][72];   // per-wave P tile (q x 64 keys)

    const ushort* Kb = Kh + (size_t)b * NQ * 256 + h * 32;
    const ushort* Vb = Vt + (size_t)bh * 32 * NQ;

    const short8 qf = *(const short8*)(Qh + (size_t)(b * NQ + q0 + lr) * 256 + h * 32 + quad * 8);

    float mrow[4] = {-1e30f, -1e30f, -1e30f, -1e30f};
    float lsum[4] = {0.f, 0.f, 0.f, 0.f};
    floatx4 accO[2] = {};
    const floatx4 zero = {0.f, 0.f, 0.f, 0.f};

    for (int k0 = 0; k0 < NQ; k0 += 64) {
        floatx4 s[4];
#pragma unroll
        for (int cb = 0; cb < 4; ++cb) {
            const short8 kf = *(const short8*)(Kb + (size_t)(k0 + cb * 16 + lr) * 256 + quad * 8);
            s[cb] = __builtin_amdgcn_mfma_f32_16x16x32_bf16(qf, kf, zero, 0, 0, 0);
        }
        float corr[4];
#pragma unroll
        for (int r = 0; r < 4; ++r) {
            float mx = fmaxf(fmaxf(s[0][r], s[1][r]), fmaxf(s[2][r], s[3][r]));
            mx = fmaxf(mx, __shfl_xor(mx, 1));
            mx = fmaxf(mx, __shfl_xor(mx, 2));
            mx = fmaxf(mx, __shfl_xor(mx, 4));
            mx = fmaxf(mx, __shfl_xor(mx, 8));
            const float mnew = fmaxf(mrow[r], mx);
            corr[r] = __expf(mrow[r] - mnew);
            mrow[r] = mnew;
        }
        float rsum[4] = {0.f, 0.f, 0.f, 0.f};
#pragma unroll
        for (int cb = 0; cb < 4; ++cb)
#pragma unroll
            for (int r = 0; r < 4; ++r) {
                const float p = __expf(s[cb][r] - mrow[r]);
                s[cb][r] = p;
                rsum[r] += p;
            }
#pragma unroll
        for (int r = 0; r < 4; ++r) {
            float t = rsum[r];
            t += __shfl_xor(t, 1);
            t += __shfl_xor(t, 2);
            t += __shfl_xor(t, 4);
            t += __shfl_xor(t, 8);
            lsum[r] = lsum[r] * corr[r] + t;
            accO[0][r] *= corr[r];
            accO[1][r] *= corr[r];
        }
#pragma unroll
        for (int cb = 0; cb < 4; ++cb)
#pragma unroll
            for (int r = 0; r < 4; ++r)
                Pl[wave][quad * 4 + r][cb * 16 + lr] = f2bf(s[cb][r]);
        // wave-private LDS; same-wave DS ordering + lgkmcnt suffice (no barrier)
#pragma unroll
        for (int kc = 0; kc < 2; ++kc) {
            const short8 pf = *(const short8*)&Pl[wave][lr][kc * 32 + quad * 8];
            const short8 v0 = *(const short8*)(Vb + (size_t)lr * NQ + k0 + kc * 32 + quad * 8);
            const short8 v1 = *(const short8*)(Vb + (size_t)(16 + lr) * NQ + k0 + kc * 32 + quad * 8);
            accO[0] = __builtin_amdgcn_mfma_f32_16x16x32_bf16(pf, v0, accO[0], 0, 0, 0);
            accO[1] = __builtin_amdgcn_mfma_f32_16x16x32_bf16(pf, v1, accO[1], 0, 0, 0);
        }
    }

    ushort* orow = Oh + (size_t)(b * NQ + q0) * 256 + h * 32;
#pragma unroll
    for (int r = 0; r < 4; ++r) {
        const float inv = 1.f / lsum[r];
        const int q = quad * 4 + r;
        orow[(size_t)q * 256 + lr]      = f2bf(accO[0][r] * inv);
        orow[(size_t)q * 256 + 16 + lr] = f2bf(accO[1][r] * inv);
    }
}

// ---------------------------------------------------------------------------
// Segmented fp32 -> bf16 conversion (weights + src), one launch.
// ---------------------------------------------------------------------------
struct CvtSeg { const float* in; ushort* out; int n4; };
struct CvtArgs { CvtSeg seg[11]; };

__global__ __launch_bounds__(256) void convert_kernel(CvtArgs args)
{
    const CvtSeg sg = args.seg[blockIdx.y];
    const int i = blockIdx.x * 256 + threadIdx.x;
    if (i < sg.n4) {
        float4 v = ((const float4*)sg.in)[i];
        ushort4 o;
        o.x = f2bf(v.x); o.y = f2bf(v.y); o.z = f2bf(v.z); o.w = f2bf(v.w);
        ((ushort4*)sg.out)[i] = o;
    }
}

// out = tgt (fp32), out_h = bf16(tgt), qadd_h = bf16(tgt + qpos)
__global__ __launch_bounds__(256) void init_out_kernel(const float* __restrict__ tgt,
                                                       const float* __restrict__ qpos,
                                                       float* __restrict__ out,
                                                       ushort* __restrict__ out_h,
                                                       ushort* __restrict__ qadd_h, int n4)
{
    const int i = blockIdx.x * 256 + threadIdx.x;
    if (i < n4) {
        float4 v = ((const float4*)tgt)[i];
        float4 p = ((const float4*)qpos)[i];
        ((float4*)out)[i] = v;
        ushort4 o, qa;
        o.x = f2bf(v.x); o.y = f2bf(v.y); o.z = f2bf(v.z); o.w = f2bf(v.w);
        qa.x = f2bf(v.x + p.x); qa.y = f2bf(v.y + p.y);
        qa.z = f2bf(v.z + p.z); qa.w = f2bf(v.w + p.w);
        ((ushort4*)out_h)[i] = o;
        ((ushort4*)qadd_h)[i] = qa;
    }
}

// ---------------------------------------------------------------------------
// Fused residual + LayerNorm -> out fp32, out_h bf16, qadd_h = bf16(ln + qpos).
// One block per row. In-place safe.
// ---------------------------------------------------------------------------
__global__ __launch_bounds__(256) void residual_ln_kernel(const float* __restrict__ x,
                                                          const float* __restrict__ t2,
                                                          const float* __restrict__ g,
                                                          const float* __restrict__ bt,
                                                          const float* __restrict__ qpos,
                                                          float* __restrict__ outp,
                                                          ushort* __restrict__ outp_h,
                                                          ushort* __restrict__ qadd_h)
{
    const int row = blockIdx.x;
    const int c = threadIdx.x;
    const size_t idx = (size_t)row * D_MODEL + c;
    float v = x[idx] + t2[idx];

    float s = v, s2 = v * v;
#pragma unroll
    for (int off = 32; off; off >>= 1) {
        s  += __shfl_xor(s,  off);
        s2 += __shfl_xor(s2, off);
    }
    __shared__ float ws[4], ws2[4];
    const int wid = c >> 6;
    if ((c & 63) == 0) { ws[wid] = s; ws2[wid] = s2; }
    __syncthreads();
    const float tot  = ws[0] + ws[1] + ws[2] + ws[3];
    const float tot2 = ws2[0] + ws2[1] + ws2[2] + ws2[3];
    const float mu  = tot * (1.f / 256.f);
    const float var = tot2 * (1.f / 256.f) - mu * mu;
    const float r = (v - mu) * rsqrtf(var + 1e-5f) * g[c] + bt[c];
    outp[idx] = r;
    outp_h[idx] = f2bf(r);
    qadd_h[idx] = f2bf(r + qpos[idx]);
}

// ---------------------------------------------------------------------------
// Deformable sampling with inline softmax over the 16 attention weights.
// Block per (b,q); thread = (head h = tid>>5, chan c = tid&31).
// ---------------------------------------------------------------------------
__global__ __launch_bounds__(256) void sample_kernel(const ushort* __restrict__ value,
                                                     const float* __restrict__ off,
                                                     const float* __restrict__ aw,
                                                     const float* __restrict__ ref,
                                                     ushort* __restrict__ outp_h)
{
    const int bq = blockIdx.x;
    const int b  = bq / NQ;
    const int h  = threadIdx.x >> 5;
    const int c  = threadIdx.x & 31;

    const float* offrow = off + (size_t)bq * 256 + h * 32;
    const float* awrow  = aw  + (size_t)bq * 128 + h * 16;
    const float* refrow = ref + (size_t)bq * 8;

    float w16[16];
    {
        float mx = -1e30f;
#pragma unroll
        for (int i = 0; i < 16; ++i) { w16[i] = awrow[i]; mx = fmaxf(mx, w16[i]); }
        float sum = 0.f;
#pragma unroll
        for (int i = 0; i < 16; ++i) { w16[i] = __expf(w16[i] - mx); sum += w16[i]; }
        const float inv = 1.f / sum;
#pragma unroll
        for (int i = 0; i < 16; ++i) w16[i] *= inv;
    }

    const int HL[4]  = {64, 32, 16, 8};
    const int WLv[4] = {64, 32, 16, 8};
    const int S0[4]  = {0, 4096, 5120, 5376};

    float acc = 0.f;
#pragma unroll
    for (int l = 0; l < 4; ++l) {
        const int Hl = HL[l], Wl = WLv[l];
        const float rx = refrow[l * 2 + 0];
        const float ry = refrow[l * 2 + 1];
        const size_t lvl_base = ((size_t)b * S_TOTAL + S0[l]);
#pragma unroll
        for (int p = 0; p < 4; ++p) {
            const float ox = offrow[l * 8 + p * 2 + 0];
            const float oy = offrow[l * 8 + p * 2 + 1];
            const float w  = w16[l * 4 + p];
            const float locx = rx + ox / (float)Wl;
            const float locy = ry + oy / (float)Hl;
            const float x = locx * (float)Wl - 0.5f;
            const float y = locy * (float)Hl - 0.5f;
            const float x0f = floorf(x), y0f = floorf(y);
            const float wx1 = x - x0f, wy1 = y - y0f;
            const int x0 = (int)x0f, y0 = (int)y0f;
#pragma unroll
            for (int dy = 0; dy < 2; ++dy) {
                const int yi = y0 + dy;
                const float wy = dy ? wy1 : (1.f - wy1);
                const bool vy = (yi >= 0) && (yi <= Hl - 1);
                const int yc = min(max(yi, 0), Hl - 1);
#pragma unroll
                for (int dx = 0; dx < 2; ++dx) {
                    const int xi = x0 + dx;
                    const float wx = dx ? wx1 : (1.f - wx1);
                    const bool vx = (xi >= 0) && (xi <= Wl - 1);
                    const int xc = min(max(xi, 0), Wl - 1);
                    const float g = bf2f(value[((lvl_base + (size_t)yc * Wl + xc)) * 256 + h * 32 + c]);
                    acc += (vx && vy) ? g * (wx * wy * w) : 0.f;
                }
            }
        }
    }
    outp_h[(size_t)bq * D_MODEL + h * 32 + c] = f2bf(acc);
}

// ---------------------------------------------------------------------------
// Host-side orchestration
// ---------------------------------------------------------------------------
extern "C" void kernel_launch(void* const* d_in, const int* in_sizes, int n_in,
                              void* d_out, int out_size, void* d_ws, size_t ws_size,
                              hipStream_t stream)
{
    const float* tgt  = (const float*)d_in[0];
    const float* qpos = (const float*)d_in[1];
    const float* refp = (const float*)d_in[2];
    const float* src  = (const float*)d_in[3];

    // ---- workspace carve-up ----
    float* bufT   = (float*)d_ws;                   // 819200 (GEMM fp32 out pre-LN)
    float* bufOff = bufT   + ROW_ELEMS;             // 819200
    float* bufAw  = bufOff + ROW_ELEMS;             // 409600

    ushort* out_h   = (ushort*)(bufAw + (size_t)M_Q * 128);
    ushort* qadd_h  = out_h   + ROW_ELEMS;
    ushort* bufX_h  = qadd_h  + ROW_ELEMS;          // attn-out / sample-out
    ushort* bufQh   = bufX_h  + ROW_ELEMS;
    ushort* bufKh   = bufQh   + ROW_ELEMS;
    ushort* bufVt   = bufKh   + ROW_ELEMS;          // V^T (b,h,d,q)
    ushort* bufF_h  = bufVt   + ROW_ELEMS;          // 3276800 ffn hidden
    ushort* bufVal  = bufF_h  + (size_t)M_Q * D_FFN;   // 2785280 deform value
    ushort* src_h   = bufVal  + (size_t)M_V * D_MODEL; // 2785280
    ushort* wpool   = src_h   + (size_t)M_V * D_MODEL;

    ushort* wq_h    = wpool;
    ushort* wk_h    = wq_h    + 393216;
    ushort* wv_h    = wk_h    + 393216;
    ushort* wo_h    = wv_h    + 393216;
    ushort* woff_h  = wo_h    + 393216;
    ushort* wattn_h = woff_h  + 393216;
    ushort* wval_h  = wattn_h + 196608;
    ushort* wout_h  = wval_h  + 393216;
    ushort* w1_h    = wout_h  + 393216;
    ushort* w2_h    = w1_h    + 1572864;

    float* out = (float*)d_out;

    // ---- conversions ----
    CvtArgs ca;
    ca.seg[0]  = { src,                    src_h,   (int)((size_t)M_V * D_MODEL / 4) };
    ca.seg[1]  = { (const float*)d_in[4],  wq_h,    393216 / 4 };
    ca.seg[2]  = { (const float*)d_in[6],  wk_h,    393216 / 4 };
    ca.seg[3]  = { (const float*)d_in[8],  wv_h,    393216 / 4 };
    ca.seg[4]  = { (const float*)d_in[10], wo_h,    393216 / 4 };
    ca.seg[5]  = { (const float*)d_in[14], woff_h,  393216 / 4 };
    ca.seg[6]  = { (const float*)d_in[16], wattn_h, 196608 / 4 };
    ca.seg[7]  = { (const float*)d_in[18], wval_h,  393216 / 4 };
    ca.seg[8]  = { (const float*)d_in[20], wout_h,  393216 / 4 };
    ca.seg[9]  = { (const float*)d_in[24], w1_h,    1572864 / 4 };
    ca.seg[10] = { (const float*)d_in[26], w2_h,    1572864 / 4 };
    convert_kernel<<<dim3(2720, 11), 256, 0, stream>>>(ca);

    init_out_kernel<<<800, 256, 0, stream>>>(tgt, qpos, out, out_h, qadd_h, (int)(ROW_ELEMS / 4));

    const float QSCALE = 0.1767766952966369f;
    const int MB_Q = M_Q / 64;   // 50
    const int MB_V = M_V / 64;   // 170

    for (int l = 0; l < NUM_LAYERS; ++l) {
        const float* sa_b_q    = (const float*)d_in[5]  + (size_t)l * 256;
        const float* sa_b_k    = (const float*)d_in[7]  + (size_t)l * 256;
        const float* sa_b_v    = (const float*)d_in[9]  + (size_t)l * 256;
        const float* sa_b_o    = (const float*)d_in[11] + (size_t)l * 256;
        const float* ln2_g     = (const float*)d_in[12] + (size_t)l * 256;
        const float* ln2_b     = (const float*)d_in[13] + (size_t)l * 256;
        const float* ca_b_off  = (const float*)d_in[15] + (size_t)l * 256;
        const float* ca_b_attn = (const float*)d_in[17] + (size_t)l * 128;
        const float* ca_b_val  = (const float*)d_in[19] + (size_t)l * 256;
        const float* ca_b_out  = (const float*)d_in[21] + (size_t)l * 256;
        const float* ln1_g     = (const float*)d_in[22] + (size_t)l * 256;
        const float* ln1_b     = (const float*)d_in[23] + (size_t)l * 256;
        const float* ffn_b1    = (const float*)d_in[25] + (size_t)l * 1024;
        const float* ffn_b2    = (const float*)d_in[27] + (size_t)l * 256;
        const float* ln3_g     = (const float*)d_in[28] + (size_t)l * 256;
        const float* ln3_b     = (const float*)d_in[29] + (size_t)l * 256;

        const ushort* wq = wq_h    + (size_t)l * 65536;
        const ushort* wk = wk_h    + (size_t)l * 65536;
        const ushort* wv = wv_h    + (size_t)l * 65536;
        const ushort* wo = wo_h    + (size_t)l * 65536;
        const ushort* wf = woff_h  + (size_t)l * 65536;
        const ushort* wa = wattn_h + (size_t)l * 32768;
        const ushort* wl = wval_h  + (size_t)l * 65536;
        const ushort* wu = wout_h  + (size_t)l * 65536;
        const ushort* w1 = w1_h    + (size_t)l * 262144;
        const ushort* w2 = w2_h    + (size_t)l * 262144;

        GArgs ga;

        // ---- QKV projections + deform value projection (one dispatch, 16 segs) ----
        for (int i = 0; i < 4; ++i) {
            ga.s[i]      = { qadd_h, wq + (size_t)i * 64 * 256, sa_b_q + i * 64, bufQh + i * 64, 256, 2, MB_Q, QSCALE };
            ga.s[4 + i]  = { qadd_h, wk + (size_t)i * 64 * 256, sa_b_k + i * 64, bufKh + i * 64, 256, 2, MB_Q, 1.f };
            ga.s[8 + i]  = { out_h,  wv + (size_t)i * 64 * 256, sa_b_v + i * 64, bufVt + (size_t)i * 64 * NQ, 256, 3, MB_Q, 1.f };
            ga.s[12 + i] = { src_h,  wl + (size_t)i * 64 * 256, ca_b_val + i * 64, bufVal + i * 64, 256, 2, MB_V, 1.f };
        }
        gemm_multi<<<dim3(MB_V, 16), 256, 0, stream>>>(ga, 256);

        attn_mfma<<<dim3(16, NQ / 64), 256, 0, stream>>>(bufQh, bufKh, bufVt, bufX_h);

        for (int i = 0; i < 4; ++i)
            ga.s[i] = { bufX_h, wo + (size_t)i * 64 * 256, sa_b_o + i * 64, bufT + i * 64, 256, 0, MB_Q, 1.f };
        gemm_multi<<<dim3(MB_Q, 4), 256, 0, stream>>>(ga, 256);

        residual_ln_kernel<<<M_Q, 256, 0, stream>>>(out, bufT, ln2_g, ln2_b, qpos, out, out_h, qadd_h);

        // ---- Deformable cross-attention ----
        for (int i = 0; i < 4; ++i)
            ga.s[i] = { qadd_h, wf + (size_t)i * 64 * 256, ca_b_off + i * 64, bufOff + i * 64, 256, 0, MB_Q, 1.f };
        for (int i = 0; i < 2; ++i)
            ga.s[4 + i] = { qadd_h, wa + (size_t)i * 64 * 256, ca_b_attn + i * 64, bufAw + i * 64, 128, 0, MB_Q, 1.f };
        gemm_multi<<<dim3(MB_Q, 6), 256, 0, stream>>>(ga, 256);

        sample_kernel<<<M_Q, 256, 0, stream>>>(bufVal, bufOff, bufAw, refp, bufX_h);

        for (int i = 0; i < 4; ++i)
            ga.s[i] = { bufX_h, wu + (size_t)i * 64 * 256, ca_b_out + i * 64, bufT + i * 64, 256, 0, MB_Q, 1.f };
        gemm_multi<<<dim3(MB_Q, 4), 256, 0, stream>>>(ga, 256);

        residual_ln_kernel<<<M_Q, 256, 0, stream>>>(out, bufT, ln1_g, ln1_b, qpos, out, out_h, qadd_h);

        // ---- FFN ----
        for (int i = 0; i < 16; ++i)
            ga.s[i] = { out_h, w1 + (size_t)i * 64 * 256, ffn_b1 + i * 64, bufF_h + i * 64, 1024, 1, MB_Q, 1.f };
        gemm_multi<<<dim3(MB_Q, 16), 256, 0, stream>>>(ga, 256);

        for (int i = 0; i < 4; ++i)
            ga.s[i] = { bufF_h, w2 + (size_t)i * 64 * 1024, ffn_b2 + i * 64, bufT + i * 64, 256, 0, MB_Q, 1.f };
        gemm_multi<<<dim3(MB_Q, 4), 256, 0, stream>>>(ga, 1024);

        residual_ln_kernel<<<M_Q, 256, 0, stream>>>(out, bufT, ln3_g, ln3_b, qpos, out, out_h, qadd_h);
    }

    (void)in_sizes; (void)n_in; (void)out_size; (void)ws_size;
}